// Round 11
// baseline (7673.936 us; speedup 1.0000x reference)
//
#include <hip/hip_runtime.h>
#include <hip/hip_bf16.h>
#include <float.h>

// ---------------------------------------------------------------------------
// Beam-search seq2seq (2-layer LSTM encoder S=512, 4-beam decoder MAXLEN=12,
// V=32000). fp32 math; bf16 only for stored logits history.
//
// R11 encoder: DATA REPLICATION to cut same-line LLC reader concurrency
// (R3 measured ~250 concurrent same-line readers ~= 5-8us; all prior
// variants had ~128 readers/line on the h data). h0 gets 16 dense replicas
// (L0 consumers use reps 0-7, L1 consumers reps 8-15 -> 16 readers/line),
// h1 gets 8 (16 readers/line). Parity double-buffer + R8's one-hop per-slice
// replicated flags (drain -> 32 flag-replica stores; consumer thread t polls
// slice t, replica w>>3). Gate reduction via __shfl_xor over 8-lane k-groups
// (k-chunks interleaved c4=q*8+kh for LDS bank spread); 3 syncthreads/step.
// ---------------------------------------------------------------------------

using ull = unsigned long long;

#define SCOPE_AGENT __HIP_MEMORY_SCOPE_AGENT

__device__ __forceinline__ float cLoad(const float* p) {
  return __hip_atomic_load(p, __ATOMIC_RELAXED, SCOPE_AGENT);
}
__device__ __forceinline__ void cStore(float* p, float v) {
  __hip_atomic_store(p, v, __ATOMIC_RELAXED, SCOPE_AGENT);
}
__device__ __forceinline__ int cLoadI(const int* p) {
  return __hip_atomic_load(p, __ATOMIC_RELAXED, SCOPE_AGENT);
}
__device__ __forceinline__ void cStoreI(int* p, int v) {
  __hip_atomic_store(p, v, __ATOMIC_RELAXED, SCOPE_AGENT);
}
__device__ __forceinline__ ull cLoad64(const ull* p) {
  return __hip_atomic_load(p, __ATOMIC_RELAXED, SCOPE_AGENT);
}
__device__ __forceinline__ void cStore64(ull* p, ull v) {
  __hip_atomic_store(p, v, __ATOMIC_RELAXED, SCOPE_AGENT);
}

__device__ __forceinline__ float2 u2f2(ull u) {
  union { ull u; float2 f; } c; c.u = u; return c.f;
}

// One-hop replicated-flag barrier for the decoder (R7/R8, unchanged).
__device__ __forceinline__ void fbar1(int* fl, int phase) {
  __syncthreads();
  if (threadIdx.x < 32)
    cStoreI(fl + (blockIdx.x * 32 + threadIdx.x) * 32, phase);
  {
    const int* f = fl + (threadIdx.x * 32 + (blockIdx.x >> 3)) * 32;
    while (cLoadI(f) < phase) {}
  }
  __syncthreads();
}

__device__ __forceinline__ float sig_(float x) { return 1.0f / (1.0f + expf(-x)); }

// top-4 sorted insert; ordering matches lax.top_k (desc value, tie -> lower idx)
__device__ __forceinline__ void ins4(float* v, int* id, float nv, int ni) {
  if (nv > v[3] || (nv == v[3] && ni < id[3])) {
    v[3] = nv; id[3] = ni;
#pragma unroll
    for (int p = 3; p > 0; --p) {
      bool sw = (v[p] > v[p - 1]) || (v[p] == v[p - 1] && id[p] < id[p - 1]);
      if (sw) {
        float t0 = v[p]; v[p] = v[p - 1]; v[p - 1] = t0;
        int t1 = id[p]; id[p] = id[p - 1]; id[p - 1] = t1;
      }
    }
  }
}

// ---------------------------------------------------------------------------
// Encoder: 256 WGs x 256 thr. WGs 0..127 = layer0 (cols 4w..4w+4), WGs
// 128..255 = layer1 (one step skewed). Thread = (b8, col4, kh8), kh in LOW
// bits. k interleave: thread kh handles f4-chunks c4 = q*8+kh.
// Data: h0rep[2][16][8b][512c], h1rep[2][8][8b][512c] (dense per-value
// replica stores by the 32 owner lanes). Flags: regF[(slice*32+rep)*32],
// value i+1 after iter i, stored after a __syncthreads vmcnt drain.
// Consumer at iter i polls all 256 slices >= i (slices>=128 only for i>=2).
// ---------------------------------------------------------------------------
struct EncP {
  const int* text; const float* emb;
  const float* Wih0; const float* Whh0; const float* bih0; const float* bhh0;
  const float* Wih1; const float* Whh1; const float* bih1; const float* bhh1;
  float* h0rep; float* h1rep; int* regF;
  float* h0f; float* h1f; float* c1f;
};

template <int KX>
__device__ void enc_run(const EncP& P, float* xcat, int w, int tid) {
  constexpr int KTOT = KX + 512;
  constexpr int ST = KTOT + 4;       // per-batch float stride
  constexpr int Q = KTOT / 32;       // f4 chunks per thread (24 / 32)
  constexpr int QX = KX / 32;        // wih portion (8 / 16)
  constexpr int L = (KX == 512) ? 1 : 0;
  constexpr int NR = L ? 8 : 16;     // data replica count for my layer's h

  const int c0 = (w & 127) * 4;
  const int kh = tid & 7, col = (tid >> 3) & 3, b = tid >> 5;
  const int frep = w >> 3;                 // flag replica (8 readers/line)
  const int drep = (w & 127) >> 4;         // data replica within class (0..7)

  const float* Wih = L ? P.Wih1 : P.Wih0;
  const float* Whh = L ? P.Whh1 : P.Whh0;
  const float4* wih4[4]; const float4* whh4[4];
  float bias4[4];
#pragma unroll
  for (int g = 0; g < 4; ++g) {
    const int row = g * 512 + c0 + col;
    wih4[g] = (const float4*)(Wih + (size_t)row * KX);
    whh4[g] = (const float4*)(Whh + (size_t)row * 512);
    bias4[g] = L ? (P.bih1[row] + P.bhh1[row]) : (P.bih0[row] + P.bhh0[row]);
  }
  float creg = 0.f;
  float* myRep = L ? P.h1rep : P.h0rep;

  // pre-zero h-part of xcat (used while recurrent h is still h_{-1}=0)
  for (int e = tid; e < 4096; e += 256)
    xcat[(e >> 9) * ST + KX + (e & 511)] = 0.f;
  __syncthreads();

  for (int i = 0; i <= 512; ++i) {
    const bool act = L ? (i >= 1) : (i < 512);
    if (act) {
      const int t = L ? (i - 1) : i;
      // ---- L0: emb gather (flag-independent) ----
      if constexpr (KX == 256) {
        for (int e = tid; e < 1024; e += 256) {
          const int b2 = e >> 7, k2 = e & 127;
          const int tokv = P.text[t * 8 + b2];
          *(float2*)(xcat + b2 * ST + 2 * k2) =
              *(const float2*)(P.emb + (size_t)tokv * 256 + 2 * k2);
        }
      }
      // ---- one-hop flag poll: thread t <-> slice t ----
      if (i >= 1) {
        const int s = tid;
        if ((s < 128) || (i >= 2)) {
          const int* f = P.regF + (s * 32 + frep) * 32;
          while (cLoadI(f) < i) {}
        }
      }
      __syncthreads();
      // ---- data reads from my replica (single-shot, batched) ----
      if constexpr (KX == 256) {
        if (i >= 1) {
          const ull* src = (const ull*)(P.h0rep +
              (size_t)(((i + 1) & 1) * 16 + drep) * 4096);
          for (int e = tid; e < 2048; e += 256) {
            const int b2 = e >> 8, k2 = e & 255;
            *(ull*)(xcat + b2 * ST + KX + 2 * k2) = cLoad64(src + b2 * 256 + k2);
          }
        }
      } else {
        {  // x = h0_{i-1}, L1 consumer class uses replicas 8..15
          const ull* src = (const ull*)(P.h0rep +
              (size_t)(((i + 1) & 1) * 16 + 8 + drep) * 4096);
          for (int e = tid; e < 2048; e += 256) {
            const int b2 = e >> 8, k2 = e & 255;
            *(ull*)(xcat + b2 * ST + 2 * k2) = cLoad64(src + b2 * 256 + k2);
          }
        }
        if (i >= 2) {  // recurrent h1_{i-2}
          const ull* src = (const ull*)(P.h1rep +
              (size_t)((i & 1) * 8 + drep) * 4096);
          for (int e = tid; e < 2048; e += 256) {
            const int b2 = e >> 8, k2 = e & 255;
            *(ull*)(xcat + b2 * ST + KX + 2 * k2) = cLoad64(src + b2 * 256 + k2);
          }
        }
      }
      __syncthreads();
      // ---- 4-gate dot over interleaved k-chunks c4 = q*8+kh ----
      float a0 = 0.f, a1 = 0.f, a2 = 0.f, a3 = 0.f;
      {
        const float4* xq = (const float4*)(xcat + b * ST);
#pragma unroll 4
        for (int q = 0; q < QX; ++q) {
          const int c4 = q * 8 + kh;
          float4 x = xq[c4];
          float4 w0 = wih4[0][c4], w1 = wih4[1][c4];
          float4 w2 = wih4[2][c4], w3 = wih4[3][c4];
          a0 = fmaf(w0.x, x.x, a0); a0 = fmaf(w0.y, x.y, a0);
          a0 = fmaf(w0.z, x.z, a0); a0 = fmaf(w0.w, x.w, a0);
          a1 = fmaf(w1.x, x.x, a1); a1 = fmaf(w1.y, x.y, a1);
          a1 = fmaf(w1.z, x.z, a1); a1 = fmaf(w1.w, x.w, a1);
          a2 = fmaf(w2.x, x.x, a2); a2 = fmaf(w2.y, x.y, a2);
          a2 = fmaf(w2.z, x.z, a2); a2 = fmaf(w2.w, x.w, a2);
          a3 = fmaf(w3.x, x.x, a3); a3 = fmaf(w3.y, x.y, a3);
          a3 = fmaf(w3.z, x.z, a3); a3 = fmaf(w3.w, x.w, a3);
        }
#pragma unroll 4
        for (int q = QX; q < Q; ++q) {
          const int c4 = q * 8 + kh;
          const int h4i = c4 - (KX >> 2);
          float4 x = xq[c4];
          float4 w0 = whh4[0][h4i], w1 = whh4[1][h4i];
          float4 w2 = whh4[2][h4i], w3 = whh4[3][h4i];
          a0 = fmaf(w0.x, x.x, a0); a0 = fmaf(w0.y, x.y, a0);
          a0 = fmaf(w0.z, x.z, a0); a0 = fmaf(w0.w, x.w, a0);
          a1 = fmaf(w1.x, x.x, a1); a1 = fmaf(w1.y, x.y, a1);
          a1 = fmaf(w1.z, x.z, a1); a1 = fmaf(w1.w, x.w, a1);
          a2 = fmaf(w2.x, x.x, a2); a2 = fmaf(w2.y, x.y, a2);
          a2 = fmaf(w2.z, x.z, a2); a2 = fmaf(w2.w, x.w, a2);
          a3 = fmaf(w3.x, x.x, a3); a3 = fmaf(w3.y, x.y, a3);
          a3 = fmaf(w3.z, x.z, a3); a3 = fmaf(w3.w, x.w, a3);
        }
      }
      // ---- butterfly reduce over the 8-lane kh group ----
      a0 += __shfl_xor(a0, 1); a0 += __shfl_xor(a0, 2); a0 += __shfl_xor(a0, 4);
      a1 += __shfl_xor(a1, 1); a1 += __shfl_xor(a1, 2); a1 += __shfl_xor(a1, 4);
      a2 += __shfl_xor(a2, 1); a2 += __shfl_xor(a2, 2); a2 += __shfl_xor(a2, 4);
      a3 += __shfl_xor(a3, 1); a3 += __shfl_xor(a3, 2); a3 += __shfl_xor(a3, 4);
      if (kh == 0) {
        const float gi = a0 + bias4[0], gf_ = a1 + bias4[1];
        const float gg = a2 + bias4[2], go = a3 + bias4[3];
        const float c2 = sig_(gf_) * creg + sig_(gi) * tanhf(gg);
        const float hv = sig_(go) * tanhf(c2);
        creg = c2;
        const int p = t & 1;
        float* dst = myRep + (size_t)p * NR * 4096 + b * 512 + c0 + col;
#pragma unroll
        for (int r = 0; r < NR; ++r) cStore(dst + (size_t)r * 4096, hv);
        if (t == 511) {
          (L ? P.h1f : P.h0f)[b * 512 + c0 + col] = hv;
          if (L) P.c1f[b * 512 + c0 + col] = c2;
        }
      }
      __syncthreads();  // drain vmcnt: replica stores at LLC before flags
      if (tid < 32) cStoreI(P.regF + (w * 32 + tid) * 32, i + 1);
    }
  }
}

__global__ __launch_bounds__(256, 1) void enc_kernel(EncP P) {
  __shared__ float xcat0[8 * 772];
  __shared__ float xcat1[8 * 1028];
  if (blockIdx.x >> 7) enc_run<512>(P, xcat1, blockIdx.x, threadIdx.x);
  else enc_run<256>(P, xcat0, blockIdx.x, threadIdx.x);
}

// ---------------------------------------------------------------------------
// prep: k_enc/v_enc projections, decoder state init
// ---------------------------------------------------------------------------
__global__ __launch_bounds__(256) void prep_kernel(
    const float* Wk, const float* bk, const float* Wv, const float* bv,
    const float* h0f, const float* h1f, const float* c1f,
    float* kenc, float* venc, float* nhb, float* ncb) {
  const int w = blockIdx.x, tid = threadIdx.x;
  if (w < 64) {
    const int o = w * 256 + tid;
    const int kv = o >> 13, l = (o >> 12) & 1, b = (o >> 9) & 7, c = o & 511;
    const float4* h4 = (const float4*)((l ? h1f : h0f) + b * 512);
    const float4* w4 = (const float4*)((kv ? Wv : Wk) + (size_t)c * 512);
    float s0 = 0.f, s1 = 0.f, s2 = 0.f, s3 = 0.f;
#pragma unroll 8
    for (int k = 0; k < 128; ++k) {
      float4 a = w4[k], x = h4[k];
      s0 = fmaf(a.x, x.x, s0); s1 = fmaf(a.y, x.y, s1);
      s2 = fmaf(a.z, x.z, s2); s3 = fmaf(a.w, x.w, s3);
    }
    (kv ? venc : kenc)[l * 4096 + b * 512 + c] =
        (kv ? bv : bk)[c] + ((s0 + s1) + (s2 + s3));
  } else {
    const int o = (w - 64) * 256 + tid;
    nhb[16384 + o] = h1f[o & 4095];
    ncb[16384 + o] = c1f[o & 4095];
  }
}

// ---------------------------------------------------------------------------
// prep2: attention algebra folds (R3-verified).
// ---------------------------------------------------------------------------
__global__ __launch_bounds__(256) void prep2_kernel(
    const float* Wq, const float* Wk, const float* Wv, const float* Wo,
    const float* bq, const float* bk, const float* bv,
    const float* kenc, const float* venc,
    float* At, float* W2, float* u, float* pvec, float* veWo, float* bvo,
    float* sl0, float* sbb) {
  const int w = blockIdx.x, tid = threadIdx.x;
#pragma unroll 1
  for (int sub = 0; sub < 2; ++sub) {
    const int d = 2 * w + sub;
    for (int cc = 0; cc < 2; ++cc) {
      const int c = tid + cc * 256;
      float s0 = 0.f, s1 = 0.f, s2 = 0.f, s3 = 0.f;
      for (int i = 0; i < 512; i += 4) {
        s0 = fmaf(Wk[(i + 0) * 512 + d], Wq[(i + 0) * 512 + c], s0);
        s1 = fmaf(Wk[(i + 1) * 512 + d], Wq[(i + 1) * 512 + c], s1);
        s2 = fmaf(Wk[(i + 2) * 512 + d], Wq[(i + 2) * 512 + c], s2);
        s3 = fmaf(Wk[(i + 3) * 512 + d], Wq[(i + 3) * 512 + c], s3);
      }
      At[(size_t)d * 512 + c] = (s0 + s1) + (s2 + s3);
    }
    for (int cc = 0; cc < 2; ++cc) {
      const int dc = tid + cc * 256;
      float s0 = 0.f, s1 = 0.f, s2 = 0.f, s3 = 0.f;
      const float* wor = Wo + (size_t)d * 512;
      for (int c2 = 0; c2 < 512; c2 += 4) {
        s0 = fmaf(wor[c2 + 0], Wv[(size_t)(c2 + 0) * 512 + dc], s0);
        s1 = fmaf(wor[c2 + 1], Wv[(size_t)(c2 + 1) * 512 + dc], s1);
        s2 = fmaf(wor[c2 + 2], Wv[(size_t)(c2 + 2) * 512 + dc], s2);
        s3 = fmaf(wor[c2 + 3], Wv[(size_t)(c2 + 3) * 512 + dc], s3);
      }
      W2[(size_t)d * 512 + dc] = (s0 + s1) + (s2 + s3);
    }
  }
  if (w == 0) {
    for (int cc = 0; cc < 2; ++cc) {
      const int c = tid + cc * 256;
      float a = 0.f;
      for (int i = 0; i < 512; ++i)
        a += Wq[i * 512 + c] * bk[i] + Wk[i * 512 + c] * bq[i];
      u[c] = a;
    }
  } else if (w <= 32) {
    const int idx = (w - 1) * 256 + tid;
    const int l = idx >> 12, b = (idx >> 9) & 7, c = idx & 511;
    const float* ke = kenc + l * 4096 + b * 512;
    float a = 0.f;
    for (int i = 0; i < 512; ++i) a = fmaf(Wq[i * 512 + c], ke[i], a);
    pvec[idx] = a;
  } else if (w <= 64) {
    const int idx = (w - 33) * 256 + tid;
    const int l = idx >> 12, b = (idx >> 9) & 7, j = idx & 511;
    const float* ve = venc + l * 4096 + b * 512;
    const float* wo = Wo + (size_t)j * 512;
    float a = 0.f;
    for (int c = 0; c < 512; ++c) a = fmaf(wo[c], ve[c], a);
    veWo[idx] = a;
  } else if (w == 65) {
    for (int cc = 0; cc < 2; ++cc) {
      const int j = tid + cc * 256;
      const float* wo = Wo + (size_t)j * 512;
      float a = 0.f;
      for (int c = 0; c < 512; ++c) a = fmaf(wo[c], bv[c], a);
      bvo[j] = a;
    }
  } else if (w == 66) {
    if (tid < 16) {
      const int l = tid >> 3, b = tid & 7;
      const float* ke = kenc + l * 4096 + b * 512;
      float a = 0.f;
      for (int i = 0; i < 512; ++i) a = fmaf(bq[i], ke[i], a);
      sl0[tid] = a;
    } else if (tid == 16) {
      float a = 0.f;
      for (int i = 0; i < 512; ++i) a = fmaf(bq[i], bk[i], a);
      sbb[0] = a;
    }
  }
}

// ---------------------------------------------------------------------------
// prep3: fold static attention terms through Wout via LDS row-tiles.
// ---------------------------------------------------------------------------
__global__ __launch_bounds__(256) void prep3_kernel(
    const float* Wout, const float* bout, const float* bo, const float* veWo,
    float* E0g, float* E1g, float* bcg) {
  __shared__ float sv[16 * 516 + 512];
  __shared__ float stg[8 * 516];
  const int w = blockIdx.x, tid = threadIdx.x;
  for (int e = tid; e < 8704; e += 256) {
    if (e < 8192) sv[(e >> 9) * 516 + (e & 511)] = veWo[e];
    else sv[16 * 516 + (e - 8192)] = bo[e - 8192];
  }
  const int cbase = w * 125;
  for (int tile = 0; tile < 16; ++tile) {
    const int r0 = tile * 8;
    __syncthreads();
    for (int e = tid; e < 1024; e += 256) {
      const int rr = e >> 7, k4 = e & 127;
      int row = r0 + rr; if (row > 124) row = 124;
      *(float4*)&stg[rr * 516 + k4 * 4] =
          *(const float4*)&Wout[(size_t)(cbase + row) * 512 + k4 * 4];
    }
    __syncthreads();
    if (tid < 136) {
      const int rr = tid / 17, sel = tid - rr * 17;
      const int row = r0 + rr;
      if (row < 125) {
        const float4* a4 = (const float4*)&stg[rr * 516];
        const float4* x4 =
            (const float4*)&sv[sel < 16 ? sel * 516 : 16 * 516];
        float s0 = 0.f, s1 = 0.f, s2 = 0.f, s3 = 0.f;
#pragma unroll 8
        for (int k = 0; k < 128; ++k) {
          float4 a = a4[k], x = x4[k];
          s0 = fmaf(a.x, x.x, s0); s1 = fmaf(a.y, x.y, s1);
          s2 = fmaf(a.z, x.z, s2); s3 = fmaf(a.w, x.w, s3);
        }
        const float s = (s0 + s1) + (s2 + s3);
        const int c = cbase + row;
        if (sel < 16) (sel < 8 ? E0g : E1g)[(size_t)(sel & 7) * 32000 + c] = s;
        else bcg[c] = s + bout[c];
      }
    }
  }
}

// ---------------------------------------------------------------------------
// Decoder: 256 WGs x 256 thr, 12 steps x 3 one-hop barriers (R8, unchanged).
// ---------------------------------------------------------------------------
struct DecP {
  const float* emb;
  const float* Wih; const float* Whh; const float* bih; const float* bhh;
  const float* Wout;
  const float* At; const float* W2; const float* u; const float* bvo;
  const float* pvec; const float* sl0; const float* sbb;
  const float* E0g; const float* E1g; const float* bcg;
  float* nhb; float* ncb;  // [2][32][512]
  float* vbuf;             // [32][512]
  float* part_s;           // [3][32][64]
  ull* pvp;                // [256][32][4] packed (val,idx)
  int* obh;                // [12][4][8]
  int* res0;               // [13][8]
  __hip_bfloat16* hist;    // [12][32][32000]
  int* fl;
};

__global__ __launch_bounds__(256, 1) void dec_kernel(DecP P) {
  __shared__ float SM[29600];
  __shared__ float gl[2][4][32];
  __shared__ float slS[32][3];
  __shared__ float wslS[96];
  __shared__ float svv[32][8][4];
  __shared__ int sii[32][8][4];
  __shared__ float rvS[32][4];
  __shared__ int rtS[32][4];
  __shared__ int resS[4][13][8];
  __shared__ int oblS[32];
  __shared__ int tokS[32];
  __shared__ float pscS[32][8];
  __shared__ float nhsS[32][8];

  const int w = blockIdx.x, tid = threadIdx.x;
  float* hs = SM;
  float* tileS = SM;
  float* vqS = SM + 16896;
  float* tvE = SM + 21120;
  int* tiE = (int*)(SM + 25344);
  int ph = 0;

  if (tid < 104) {
    for (int n = 0; n < 4; ++n) resS[n][tid >> 3][tid & 7] = 1;
  }

  auto do_select = [&](int tt) {
    {
      const int r = tid >> 3, ch = tid & 7;
      float m4[4] = {-FLT_MAX, -FLT_MAX, -FLT_MAX, -FLT_MAX};
      int mi[4] = {0x7fffffff, 0x7fffffff, 0x7fffffff, 0x7fffffff};
      for (int g = 0; g < 4; ++g) {
        ull pk[32];
#pragma unroll
        for (int z = 0; z < 32; ++z) {
          const int wg = ch * 32 + g * 8 + (z >> 2);
          pk[z] = cLoad64(P.pvp + wg * 128 + r * 4 + (z & 3));
        }
#pragma unroll
        for (int z = 0; z < 32; ++z)
          ins4(m4, mi, __uint_as_float((unsigned)(pk[z] >> 32)),
               (int)(unsigned)(pk[z] & 0xffffffffu));
      }
#pragma unroll
      for (int k = 0; k < 4; ++k) { svv[r][ch][k] = m4[k]; sii[r][ch][k] = mi[k]; }
    }
    __syncthreads();
    if (tid < 32) {
      float m4[4] = {-FLT_MAX, -FLT_MAX, -FLT_MAX, -FLT_MAX};
      int mi[4] = {0x7fffffff, 0x7fffffff, 0x7fffffff, 0x7fffffff};
      for (int g2 = 0; g2 < 8; ++g2)
#pragma unroll
        for (int k = 0; k < 4; ++k) ins4(m4, mi, svv[tid][g2][k], sii[tid][g2][k]);
#pragma unroll
      for (int k = 0; k < 4; ++k) { rvS[tid][k] = m4[k]; rtS[tid][k] = mi[k]; }
    }
    __syncthreads();
    if (tid < 8) {
      const int b2 = tid;
      unsigned used = 0;
      int obl_[4], tkl_[4];
#pragma unroll
      for (int sel = 0; sel < 4; ++sel) {
        float bestv = -FLT_MAX; int bestj = -1;
        for (int j = 0; j < 16; ++j) {
          if (used & (1u << j)) continue;
          float vv = rvS[(j >> 2) * 8 + b2][j & 3];
          if (vv > bestv) { bestv = vv; bestj = j; }
        }
        used |= 1u << bestj;
        const int obn = bestj >> 2;
        obl_[sel] = obn;
        tkl_[sel] = rtS[obn * 8 + b2][bestj & 3];
        oblS[sel * 8 + b2] = obn;
        tokS[sel * 8 + b2] = tkl_[sel];
        if (w == 0) P.obh[tt * 32 + sel * 8 + b2] = obn;
      }
      if (w == 0) {
        int tmp[4][13];
        for (int n2 = 0; n2 < 4; ++n2)
          for (int s2 = 0; s2 < 13; ++s2) tmp[n2][s2] = resS[obl_[n2]][s2][b2];
        for (int n2 = 0; n2 < 4; ++n2)
          for (int s2 = 0; s2 < 13; ++s2) resS[n2][s2][b2] = tmp[n2][s2];
        for (int n2 = 0; n2 < 4; ++n2) resS[n2][tt + 1][b2] = tkl_[n2];
      }
    }
    __syncthreads();
    if (tt == 11 && w == 0 && tid < 104)
      P.res0[tid] = resS[0][tid >> 3][tid & 7];
  };

  for (int t = 0; t < 12; ++t) {
    const int curOff = (t & 1) * 16384, prevOff = ((t + 1) & 1) * 16384;

    if (t == 0) {
      __syncthreads();
      if (tid < 32) { oblS[tid] = tid >> 3; tokS[tid] = 1; }
      __syncthreads();
    } else {
      do_select(t - 1);
    }
    // ===== A: LSTM gates + cell with backpointer gather =====
    {
      const int col_l = tid >> 7, gate = (tid >> 5) & 3, nb = tid & 31;
      const int col = 2 * w + col_l;
      const int row = gate * 512 + col;
      for (int e = tid; e < 2048; e += 256) {
        const int nb2 = e >> 6, kf = e & 63;
        float4 v = *((const float4*)(P.emb + (size_t)tokS[nb2] * 256) + kf);
        *((float4*)hs + nb2 * 65 + kf) = v;
      }
      __syncthreads();
      float s0 = 0.f, s1 = 0.f, s2 = 0.f, s3 = 0.f;
      {
        const float4* a4 = (const float4*)(P.Wih + (size_t)row * 256);
        const float4* x4 = (const float4*)hs + nb * 65;
#pragma unroll 8
        for (int k = 0; k < 64; ++k) {
          float4 a = a4[k], x = x4[k];
          s0 = fmaf(a.x, x.x, s0); s1 = fmaf(a.y, x.y, s1);
          s2 = fmaf(a.z, x.z, s2); s3 = fmaf(a.w, x.w, s3);
        }
      }
      float acc = P.bih[row] + P.bhh[row];
      const ull* hsrc = (const ull*)(P.nhb + prevOff);
      const float4* w4row = (const float4*)(P.Whh + (size_t)row * 512);
      for (int ck = 0; ck < 2; ++ck) {
        __syncthreads();
        for (int e = tid; e < 4096; e += 256) {
          const int nb2 = e >> 7, k2 = e & 127;
          const int srow = oblS[nb2] * 8 + (nb2 & 7);
          ull v = cLoad64(hsrc + srow * 256 + ck * 128 + k2);
          *(ull*)(hs + nb2 * 260 + 2 * k2) = v;
        }
        __syncthreads();
        const float4* h4 = (const float4*)hs + nb * 65;
        const float4* w4 = w4row + ck * 64;
#pragma unroll 8
        for (int k = 0; k < 64; ++k) {
          float4 a = w4[k], x = h4[k];
          s0 = fmaf(a.x, x.x, s0); s1 = fmaf(a.y, x.y, s1);
          s2 = fmaf(a.z, x.z, s2); s3 = fmaf(a.w, x.w, s3);
        }
      }
      acc += (s0 + s1) + (s2 + s3);
      gl[col_l][gate][nb] = acc;
      __syncthreads();
      if (tid < 64) {
        const int cc = tid >> 5, nb2 = tid & 31;
        const int col2 = 2 * w + cc;
        float gi = gl[cc][0][nb2], gf_ = gl[cc][1][nb2];
        float gg = gl[cc][2][nb2], go = gl[cc][3][nb2];
        const int srow = oblS[nb2] * 8 + (nb2 & 7);
        float cold = cLoad(P.ncb + prevOff + srow * 512 + col2);
        float c2 = sig_(gf_) * cold + sig_(gi) * tanhf(gg);
        float hv = sig_(go) * tanhf(c2);
        cStore(P.nhb + curOff + nb2 * 512 + col2, hv);
        cStore(P.ncb + curOff + nb2 * 512 + col2, c2);
      }
    }
    fbar1(P.fl, ++ph);

    // ===== B: p=0 -> score partials (At fold); p=1 -> vbuf (W2 fold) =====
    if (w < 128) {
      const int p = w >> 6, cb = w & 63;
      const int col_l = tid >> 5, nb = tid & 31;
      const int col = cb * 8 + col_l;
      const float* W = (p ? P.W2 : P.At) + (size_t)col * 512;
      float acc = (p ? P.bvo : P.u)[col];
      {
        const float4* w4row = (const float4*)W;
        float s0 = 0.f, s1 = 0.f, s2 = 0.f, s3 = 0.f;
        for (int ck = 0; ck < 2; ++ck) {
          __syncthreads();
          const ull* s8 = (const ull*)(P.nhb + curOff);
          for (int e = tid; e < 4096; e += 256) {
            const int nb2 = e >> 7, k2 = e & 127;
            ull v = cLoad64(s8 + nb2 * 256 + ck * 128 + k2);
            *(ull*)(hs + nb2 * 260 + 2 * k2) = v;
          }
          __syncthreads();
          const float4* h4 = (const float4*)hs + nb * 65;
          const float4* w4 = w4row + ck * 64;
#pragma unroll 8
          for (int k = 0; k < 64; ++k) {
            float4 a = w4[k], x = h4[k];
            s0 = fmaf(a.x, x.x, s0); s1 = fmaf(a.y, x.y, s1);
            s2 = fmaf(a.z, x.z, s2); s3 = fmaf(a.w, x.w, s3);
          }
        }
        acc += (s0 + s1) + (s2 + s3);
      }
      if (p) {
        cStore(P.vbuf + nb * 512 + col, acc);
      } else {
        const float nhv = cLoad(P.nhb + curOff + nb * 512 + col);
        pscS[nb][col_l] = nhv * acc;
        nhsS[nb][col_l] = nhv;
        __syncthreads();
        if (tid < 32) {
          const int nb2 = tid, b = nb2 & 7;
          float s2a = 0.f, l0 = 0.f, l1 = 0.f;
#pragma unroll
          for (int i2 = 0; i2 < 8; ++i2) {
            s2a += pscS[nb2][i2];
            const float nv = nhsS[nb2][i2];
            l0 = fmaf(nv, P.pvec[b * 512 + cb * 8 + i2], l0);
            l1 = fmaf(nv, P.pvec[4096 + b * 512 + cb * 8 + i2], l1);
          }
          cStore(P.part_s + (0 * 32 + nb2) * 64 + cb, l0);
          cStore(P.part_s + (1 * 32 + nb2) * 64 + cb, l1);
          cStore(P.part_s + (2 * 32 + nb2) * 64 + cb, s2a);
        }
      }
    }
    fbar1(P.fl, ++ph);

    // ===== E: softmax (from partials) + logits via LDS-tiled Wout + top-4 ==
    {
      const int cbase = w * 125;
      if (tid < 96) {
        const int nb = tid / 3, l = tid - (tid / 3) * 3, b = nb & 7;
        const ull* ps = (const ull*)(P.part_s + (l * 32 + nb) * 64);
        ull pk[32];
#pragma unroll
        for (int z = 0; z < 32; ++z) pk[z] = cLoad64(ps + z);
        float s = 0.f;
#pragma unroll
        for (int z = 0; z < 32; ++z) { float2 f = u2f2(pk[z]); s += f.x + f.y; }
        const float bias = (l < 2) ? P.sl0[l * 8 + b] : P.sbb[0];
        slS[nb][l] = (s + bias) * (1.0f / sqrtf(512.0f));
      }
      __syncthreads();
      if (tid < 32) {
        float a = slS[tid][0], b2 = slS[tid][1], c3 = slS[tid][2];
        float m = fmaxf(a, fmaxf(b2, c3));
        float e0 = expf(a - m), e1 = expf(b2 - m), e2 = expf(c3 - m);
        float inv = 1.0f / (e0 + e1 + e2);
        wslS[tid * 3 + 0] = e0 * inv;
        wslS[tid * 3 + 1] = e1 * inv;
        wslS[tid * 3 + 2] = e2 * inv;
      }
      const int rg = tid >> 3, ng = tid & 7;
      float acc[4][4];
#pragma unroll
      for (int i = 0; i < 4; ++i)
#pragma unroll
        for (int j = 0; j < 4; ++j) acc[i][j] = 0.f;
      for (int q = 0; q < 4; ++q) {
        __syncthreads();
        for (int e = tid; e < 1024; e += 256) {
          const int nb = e >> 5, kf = e & 31;
          ull u0 = cLoad64((const ull*)(P.vbuf + nb * 512 + q * 128 + kf * 4));
          ull u1 = cLoad64((const ull*)(P.vbuf + nb * 512 + q * 128 + kf * 4 + 2));
          float2 a = u2f2(u0), b2 = u2f2(u1);
          float4 v = {a.x, a.y, b2.x, b2.y};
          *(float4*)(vqS + (nb & 3) * 1056 + (nb >> 2) * 132 + kf * 4) = v;
        }
        for (int it = 0; it < 16; ++it) {
          const int idx = it * 256 + tid;
          if (idx < 4000) {
            const int r = idx >> 5, kf = idx & 31;
            float4 v = *(const float4*)(P.Wout + (size_t)(cbase + r) * 512 +
                                        q * 128 + kf * 4);
            *(float4*)(tileS + (r & 3) * 4224 + (r >> 2) * 132 + kf * 4) = v;
          }
        }
        __syncthreads();
        for (int kf = 0; kf < 32; ++kf) {
          float4 xv[4], wv[4];
#pragma unroll
          for (int j = 0; j < 4; ++j)
            xv[j] = *(const float4*)(vqS + j * 1056 + ng * 132 + kf * 4);
#pragma unroll
          for (int i = 0; i < 4; ++i)
            wv[i] = *(const float4*)(tileS + i * 4224 + rg * 132 + kf * 4);
#pragma unroll
          for (int i = 0; i < 4; ++i)
#pragma unroll
            for (int j = 0; j < 4; ++j) {
              float a = acc[i][j];
              a = fmaf(wv[i].x, xv[j].x, a); a = fmaf(wv[i].y, xv[j].y, a);
              a = fmaf(wv[i].z, xv[j].z, a); a = fmaf(wv[i].w, xv[j].w, a);
              acc[i][j] = a;
            }
        }
      }
      __syncthreads();
      float w0w[4], w1w[4], w2w[4];
#pragma unroll
      for (int j = 0; j < 4; ++j) {
        const int nb = ng * 4 + j;
        w0w[j] = wslS[nb * 3 + 0]; w1w[j] = wslS[nb * 3 + 1]; w2w[j] = wslS[nb * 3 + 2];
      }
      float v4[4][4]; int i4[4][4];
#pragma unroll
      for (int j = 0; j < 4; ++j)
#pragma unroll
        for (int k = 0; k < 4; ++k) { v4[j][k] = -FLT_MAX; i4[j][k] = 0x7fffffff; }
#pragma unroll
      for (int i = 0; i < 4; ++i) {
        const int r = rg * 4 + i;
        if (r < 125) {
          const int c = cbase + r;
          const float bcv = P.bcg[c];
#pragma unroll
          for (int j = 0; j < 4; ++j) {
            const int nb = ng * 4 + j, b = nb & 7;
            const float e0 = P.E0g[(size_t)b * 32000 + c];
            const float e1 = P.E1g[(size_t)b * 32000 + c];
            const float L = fmaf(w2w[j], acc[i][j],
                                 fmaf(w0w[j], e0, fmaf(w1w[j], e1, bcv)));
            P.hist[(size_t)t * 1024000 + (size_t)nb * 32000 + c] = __float2bfloat16(L);
            ins4(v4[j], i4[j], L, c);
          }
        }
      }
#pragma unroll
      for (int j = 0; j < 4; ++j)
#pragma unroll
        for (int k = 0; k < 4; ++k) {
          tvE[(ng * 4 + j) * 132 + rg * 4 + k] = v4[j][k];
          tiE[(ng * 4 + j) * 132 + rg * 4 + k] = i4[j][k];
        }
      __syncthreads();
      if (tid < 32) {
        float m4[4] = {-FLT_MAX, -FLT_MAX, -FLT_MAX, -FLT_MAX};
        int mi[4] = {0x7fffffff, 0x7fffffff, 0x7fffffff, 0x7fffffff};
        for (int e = 0; e < 128; ++e)
          ins4(m4, mi, tvE[tid * 132 + e], tiE[tid * 132 + e]);
#pragma unroll
        for (int k = 0; k < 4; ++k) {
          ull pk = ((ull)__float_as_uint(m4[k]) << 32) | (unsigned)mi[k];
          cStore64(P.pvp + w * 128 + tid * 4 + k, pk);
        }
      }
    }
    fbar1(P.fl, ++ph);
  }
  if (w == 0) do_select(11);
}

// ---------------------------------------------------------------------------
// Output assembly (unchanged).
// ---------------------------------------------------------------------------
__global__ __launch_bounds__(256) void out_kernel(const __hip_bfloat16* hist,
                                                  const int* obh, const int* res0,
                                                  float* out) {
  __shared__ float sh[13 * 1000];
  __shared__ int sbArr[12];
  const int w = blockIdx.x, tid = threadIdx.x;
  const int b = w >> 5, v0 = (w & 31) * 1000;
  if (tid == 0) {
    int beta = 0;
    for (int t = 11; t >= 0; --t) {
      const int sb = obh[t * 32 + beta * 8 + b];
      sbArr[t] = sb;
      beta = sb;
    }
  }
  __syncthreads();
  for (int e = tid; e < 12000; e += 256) {
    const int t = e / 1000, vv = e - t * 1000;
    sh[(t + 1) * 1000 + vv] = __bfloat162float(
        hist[(size_t)(t * 32 + sbArr[t] * 8 + b) * 32000 + v0 + vv]);
  }
  for (int e = tid; e < 1000; e += 256) sh[e] = (v0 + e == 1) ? 1.0f : 0.0f;
  __syncthreads();
  float* base = out + 104 + (size_t)(b * 32000 + v0) * 13;
  for (int o = tid; o < 13000; o += 256) {
    const int v = o / 13, t = o - v * 13;
    base[o] = sh[t * 1000 + v];
  }
  if (w == 0 && tid < 104) {
    out[(tid & 7) * 13 + (tid >> 3)] = (float)res0[tid];
  }
}

// ---------------------------------------------------------------------------
extern "C" void kernel_launch(void* const* d_in, const int* in_sizes, int n_in,
                              void* d_out, int out_size, void* d_ws, size_t ws_size,
                              hipStream_t stream) {
  const int* text  = (const int*)d_in[0];
  const float* embE = (const float*)d_in[1];
  const float* embD = (const float*)d_in[2];
  const float* Wih0 = (const float*)d_in[3];
  const float* Whh0 = (const float*)d_in[4];
  const float* bih0 = (const float*)d_in[5];
  const float* bhh0 = (const float*)d_in[6];
  const float* Wih1 = (const float*)d_in[7];
  const float* Whh1 = (const float*)d_in[8];
  const float* bih1 = (const float*)d_in[9];
  const float* bhh1 = (const float*)d_in[10];
  const float* dWih = (const float*)d_in[11];
  const float* dWhh = (const float*)d_in[12];
  const float* dbih = (const float*)d_in[13];
  const float* dbhh = (const float*)d_in[14];
  const float* Wq = (const float*)d_in[15];
  const float* bq = (const float*)d_in[16];
  const float* Wk = (const float*)d_in[17];
  const float* bk = (const float*)d_in[18];
  const float* Wv = (const float*)d_in[19];
  const float* bv = (const float*)d_in[20];
  const float* Wo = (const float*)d_in[21];
  const float* bo = (const float*)d_in[22];
  const float* Wout = (const float*)d_in[23];
  const float* bout = (const float*)d_in[24];

  char* ws = (char*)d_ws;
  size_t off = 0;
  auto alloc = [&](size_t bytes) -> char* {
    off = (off + 511) & ~(size_t)511;
    char* p = ws + off;
    off += bytes;
    return p;
  };
  float* h0rep = (float*)alloc((size_t)2 * 16 * 4096 * 4);  // 512 KB
  float* h1rep = (float*)alloc((size_t)2 * 8 * 4096 * 4);   // 256 KB
  int* regF   = (int*)alloc((size_t)262144 * 4);            // [256][32] lines
  int* decFl  = (int*)alloc((size_t)262144 * 4);            // [256][32] lines
  float* h0f  = (float*)alloc(4096 * 4);
  float* h1f  = (float*)alloc(4096 * 4);
  float* c1f  = (float*)alloc(4096 * 4);
  float* kenc = (float*)alloc(8192 * 4);
  float* venc = (float*)alloc(8192 * 4);
  float* At   = (float*)alloc((size_t)262144 * 4);
  float* W2   = (float*)alloc((size_t)262144 * 4);
  float* u    = (float*)alloc(512 * 4);
  float* pvec = (float*)alloc(8192 * 4);
  float* veWo = (float*)alloc(8192 * 4);
  float* bvo  = (float*)alloc(512 * 4);
  float* sl0  = (float*)alloc(16 * 4);
  float* sbb  = (float*)alloc(32 * 4);
  float* E0g  = (float*)alloc((size_t)256000 * 4);
  float* E1g  = (float*)alloc((size_t)256000 * 4);
  float* bcg  = (float*)alloc(32000 * 4);
  float* nhb  = (float*)alloc(2 * 16384 * 4);
  float* ncb  = (float*)alloc(2 * 16384 * 4);
  float* vbuf = (float*)alloc(16384 * 4);
  float* part_s = (float*)alloc(6144 * 4);
  ull* pvp    = (ull*)alloc((size_t)32768 * 8);
  int* obh    = (int*)alloc(384 * 4);
  int* res0   = (int*)alloc(104 * 4);
  __hip_bfloat16* hist = (__hip_bfloat16*)alloc((size_t)12288000 * 2);
  if (off > ws_size) return;  // ~34 MB required

  // only the monotonic flag arrays need re-zeroing each launch (all h-replica
  // slots are flag-gated and rewritten before any read)
  hipMemsetAsync(regF, 0, (size_t)262144 * 4, stream);
  hipMemsetAsync(decFl, 0, (size_t)262144 * 4, stream);

  EncP ep{text, embE, Wih0, Whh0, bih0, bhh0, Wih1, Whh1, bih1, bhh1,
          h0rep, h1rep, regF, h0f, h1f, c1f};
  enc_kernel<<<256, 256, 0, stream>>>(ep);

  prep_kernel<<<128, 256, 0, stream>>>(Wk, bk, Wv, bv, h0f, h1f, c1f, kenc, venc,
                                       nhb, ncb);
  prep2_kernel<<<256, 256, 0, stream>>>(Wq, Wk, Wv, Wo, bq, bk, bv, kenc, venc,
                                        At, W2, u, pvec, veWo, bvo, sl0, sbb);
  prep3_kernel<<<256, 256, 0, stream>>>(Wout, bout, bo, veWo, E0g, E1g, bcg);

  DecP dp{embD, dWih, dWhh, dbih, dbhh, Wout,
          At, W2, u, bvo, pvec, sl0, sbb, E0g, E1g, bcg,
          nhb, ncb, vbuf, part_s, pvp, obh, res0, hist, decFl};
  dec_kernel<<<256, 256, 0, stream>>>(dp);

  out_kernel<<<256, 256, 0, stream>>>(hist, obh, res0, (float*)d_out);
}

// Round 12
// 6272.187 us; speedup vs baseline: 1.2235x; 1.2235x over previous
//
#include <hip/hip_runtime.h>
#include <hip/hip_bf16.h>
#include <float.h>

// ---------------------------------------------------------------------------
// Beam-search seq2seq (2-layer LSTM encoder S=512, 4-beam decoder MAXLEN=12,
// V=32000). fp32 math; bf16 only for stored logits history.
//
// R12 = R10 data/sync structure (zero-flag write-once dataflow + batched
// sentinel polling; best measured enc) + HEATER EXPERIMENT: 256 extra
// heater WGs (grid 512, 2 WGs/CU) spin pure-register FMAs to drive
// VALUBusy -> ~100% and test whether the ~7us/step residual is a DVFS
// artifact (R10 arithmetic: VALUBusy 17.4% x 8.8us ~= 1.5us busy for
// ~1600 cycles of work => shader clock ~1.0 GHz). Heaters exit via a
// done-counter (each real WG adds 1 at end); real waves take setprio(1).
// Decoder/preps/out byte-identical to R10.
// ---------------------------------------------------------------------------

using ull = unsigned long long;

#define SCOPE_AGENT __HIP_MEMORY_SCOPE_AGENT

__device__ __forceinline__ float cLoad(const float* p) {
  return __hip_atomic_load(p, __ATOMIC_RELAXED, SCOPE_AGENT);
}
__device__ __forceinline__ void cStore(float* p, float v) {
  __hip_atomic_store(p, v, __ATOMIC_RELAXED, SCOPE_AGENT);
}
__device__ __forceinline__ int cLoadI(const int* p) {
  return __hip_atomic_load(p, __ATOMIC_RELAXED, SCOPE_AGENT);
}
__device__ __forceinline__ void cStoreI(int* p, int v) {
  __hip_atomic_store(p, v, __ATOMIC_RELAXED, SCOPE_AGENT);
}
__device__ __forceinline__ ull cLoad64(const ull* p) {
  return __hip_atomic_load(p, __ATOMIC_RELAXED, SCOPE_AGENT);
}
__device__ __forceinline__ void cStore64(ull* p, ull v) {
  __hip_atomic_store(p, v, __ATOMIC_RELAXED, SCOPE_AGENT);
}

__device__ __forceinline__ float2 u2f2(ull u) {
  union { ull u; float2 f; } c; c.u = u; return c.f;
}

__device__ __forceinline__ bool isSent(ull v) {
  return (unsigned)v == 0xFFFFFFFFu || (unsigned)(v >> 32) == 0xFFFFFFFFu;
}

// One-hop replicated-flag barrier for the decoder (R7/R8, unchanged).
__device__ __forceinline__ void fbar1(int* fl, int phase) {
  __syncthreads();
  if (threadIdx.x < 32)
    cStoreI(fl + (blockIdx.x * 32 + threadIdx.x) * 32, phase);
  {
    const int* f = fl + (threadIdx.x * 32 + (blockIdx.x >> 3)) * 32;
    while (cLoadI(f) < phase) {}
  }
  __syncthreads();
}

__device__ __forceinline__ float sig_(float x) { return 1.0f / (1.0f + expf(-x)); }

// top-4 sorted insert; ordering matches lax.top_k (desc value, tie -> lower idx)
__device__ __forceinline__ void ins4(float* v, int* id, float nv, int ni) {
  if (nv > v[3] || (nv == v[3] && ni < id[3])) {
    v[3] = nv; id[3] = ni;
#pragma unroll
    for (int p = 3; p > 0; --p) {
      bool sw = (v[p] > v[p - 1]) || (v[p] == v[p - 1] && id[p] < id[p - 1]);
      if (sw) {
        float t0 = v[p]; v[p] = v[p - 1]; v[p - 1] = t0;
        int t1 = id[p]; id[p] = id[p - 1]; id[p - 1] = t1;
      }
    }
  }
}

// ---------------------------------------------------------------------------
// Encoder (R10): 256 real WGs + 256 heater WGs. Real: WGs 0..127 = layer0,
// 128..255 = layer1. Zero-flag dataflow: h{0,1}hist[513][8][512] sentinel-
// initialized (0xFF); consumers batch-load all slots in parallel, re-poll
// only sentinel stragglers.
// ---------------------------------------------------------------------------
struct EncP {
  const int* text; const float* emb;
  const float* Wih0; const float* Whh0; const float* bih0; const float* bhh0;
  const float* Wih1; const float* Whh1; const float* bih1; const float* bhh1;
  float* h0hist; float* h1hist;   // [513][4096] each, sentinel-initialized
  float* h0f; float* h1f; float* c1f;
  int* done;                       // heater exit counter
};

template <int KX>
__device__ void enc_run(const EncP& P, float* xcat, int w, int tid) {
  constexpr int KTOT = KX + 512;
  constexpr int ST = KTOT + 4;       // per-batch stride (ST%32==4)
  constexpr int KSL = KTOT / 8;
  constexpr int Q = KSL / 4;
  constexpr int L = (KX == 512) ? 1 : 0;
  __shared__ float part[16 * 8 * 8];
  __shared__ float gl[128];

  const int c0 = (w & 127) * 4;
  const int kh = tid >> 5, col = (tid >> 3) & 3, b = tid & 7;
  const int kbase = kh * KSL;

  const float* Wih = L ? P.Wih1 : P.Wih0;
  const float* Whh = L ? P.Whh1 : P.Whh0;
  const float4* wih4[4]; const float4* whh4[4];
#pragma unroll
  for (int g = 0; g < 4; ++g) {
    const int row = g * 512 + c0 + col;
    wih4[g] = (const float4*)(Wih + (size_t)row * KX);
    whh4[g] = (const float4*)(Whh + (size_t)row * 512);
  }
  float bsum = 0.f;
  if (tid < 128) {
    const int r = tid >> 3;
    const int row = (r & 3) * 512 + c0 + (r >> 2);
    bsum = (L ? P.bih1[row] + P.bhh1[row] : P.bih0[row] + P.bhh0[row]);
  }
  float creg = 0.f;
  float* myHist = L ? P.h1hist : P.h0hist;

  int qx = (KX - kbase) / 4;
  qx = qx < 0 ? 0 : (qx > Q ? Q : qx);

  // pre-zero the h-part of xcat (used at t=0 where h_{-1}=0)
  for (int e = tid; e < 4096; e += 256)
    xcat[(e >> 9) * ST + KX + (e & 511)] = 0.f;
  __syncthreads();

  for (int t = 0; t < 512; ++t) {
    // ---- stage inputs (batched parallel loads + straggler re-poll) ----
    if constexpr (KX == 256) {
      for (int e = tid; e < 1024; e += 256) {
        const int b2 = e >> 7, k2 = e & 127;
        const int tokv = P.text[t * 8 + b2];
        *(float2*)(xcat + b2 * ST + 2 * k2) =
            *(const float2*)(P.emb + (size_t)tokv * 256 + 2 * k2);
      }
      if (t >= 1) {
        const ull* hq = (const ull*)(myHist + (size_t)t * 4096) + tid;
        ull v[8];
#pragma unroll
        for (int z = 0; z < 8; ++z) v[z] = cLoad64(hq + z * 256);
        for (;;) {
          bool any = false;
#pragma unroll
          for (int z = 0; z < 8; ++z)
            if (isSent(v[z])) { v[z] = cLoad64(hq + z * 256); any = true; }
          if (!any) break;
        }
#pragma unroll
        for (int z = 0; z < 8; ++z)
          *(ull*)(xcat + z * ST + KX + 2 * tid) = v[z];
      }
    } else {
      const ull* xq0 = (const ull*)(P.h0hist + (size_t)(t + 1) * 4096) + tid;
      const ull* hq = (const ull*)(P.h1hist + (size_t)t * 4096) + tid;
      ull vx[8], vh[8];
#pragma unroll
      for (int z = 0; z < 8; ++z) vx[z] = cLoad64(xq0 + z * 256);
      if (t >= 1) {
#pragma unroll
        for (int z = 0; z < 8; ++z) vh[z] = cLoad64(hq + z * 256);
      }
      for (;;) {
        bool any = false;
#pragma unroll
        for (int z = 0; z < 8; ++z)
          if (isSent(vx[z])) { vx[z] = cLoad64(xq0 + z * 256); any = true; }
        if (t >= 1) {
#pragma unroll
          for (int z = 0; z < 8; ++z)
            if (isSent(vh[z])) { vh[z] = cLoad64(hq + z * 256); any = true; }
        }
        if (!any) break;
      }
#pragma unroll
      for (int z = 0; z < 8; ++z)
        *(ull*)(xcat + z * ST + 2 * tid) = vx[z];
      if (t >= 1) {
#pragma unroll
        for (int z = 0; z < 8; ++z)
          *(ull*)(xcat + z * ST + KX + 2 * tid) = vh[z];
      }
    }
    __syncthreads();

    // ---- 4-gate dot over this thread's k-slice ----
    float a0 = 0.f, a1 = 0.f, a2 = 0.f, a3 = 0.f;
    {
      const float4* xq = (const float4*)(xcat + b * ST + kbase);
      const int iw = kbase >> 2, ih = (kbase - KX) >> 2;
#pragma unroll 4
      for (int q = 0; q < qx; ++q) {
        float4 x = xq[q];
        float4 w0 = wih4[0][iw + q], w1 = wih4[1][iw + q];
        float4 w2 = wih4[2][iw + q], w3 = wih4[3][iw + q];
        a0 = fmaf(w0.x, x.x, a0); a0 = fmaf(w0.y, x.y, a0);
        a0 = fmaf(w0.z, x.z, a0); a0 = fmaf(w0.w, x.w, a0);
        a1 = fmaf(w1.x, x.x, a1); a1 = fmaf(w1.y, x.y, a1);
        a1 = fmaf(w1.z, x.z, a1); a1 = fmaf(w1.w, x.w, a1);
        a2 = fmaf(w2.x, x.x, a2); a2 = fmaf(w2.y, x.y, a2);
        a2 = fmaf(w2.z, x.z, a2); a2 = fmaf(w2.w, x.w, a2);
        a3 = fmaf(w3.x, x.x, a3); a3 = fmaf(w3.y, x.y, a3);
        a3 = fmaf(w3.z, x.z, a3); a3 = fmaf(w3.w, x.w, a3);
      }
#pragma unroll 4
      for (int q = qx; q < Q; ++q) {
        float4 x = xq[q];
        float4 w0 = whh4[0][ih + q], w1 = whh4[1][ih + q];
        float4 w2 = whh4[2][ih + q], w3 = whh4[3][ih + q];
        a0 = fmaf(w0.x, x.x, a0); a0 = fmaf(w0.y, x.y, a0);
        a0 = fmaf(w0.z, x.z, a0); a0 = fmaf(w0.w, x.w, a0);
        a1 = fmaf(w1.x, x.x, a1); a1 = fmaf(w1.y, x.y, a1);
        a1 = fmaf(w1.z, x.z, a1); a1 = fmaf(w1.w, x.w, a1);
        a2 = fmaf(w2.x, x.x, a2); a2 = fmaf(w2.y, x.y, a2);
        a2 = fmaf(w2.z, x.z, a2); a2 = fmaf(w2.w, x.w, a2);
        a3 = fmaf(w3.x, x.x, a3); a3 = fmaf(w3.y, x.y, a3);
        a3 = fmaf(w3.z, x.z, a3); a3 = fmaf(w3.w, x.w, a3);
      }
    }
    part[((col * 4 + 0) * 8 + b) * 8 + kh] = a0;
    part[((col * 4 + 1) * 8 + b) * 8 + kh] = a1;
    part[((col * 4 + 2) * 8 + b) * 8 + kh] = a2;
    part[((col * 4 + 3) * 8 + b) * 8 + kh] = a3;
    __syncthreads();
    if (tid < 128) {
      const int r = tid >> 3, b2 = tid & 7;
      const float4* pp = (const float4*)(part + (r * 8 + b2) * 8);
      float4 p0 = pp[0], p1 = pp[1];
      gl[r * 8 + b2] =
          bsum + (((p0.x + p0.y) + (p0.z + p0.w)) + ((p1.x + p1.y) + (p1.z + p1.w)));
    }
    __syncthreads();
    if (tid < 32) {
      const int cc = tid >> 3, b2 = tid & 7;
      float gi = gl[(cc * 4 + 0) * 8 + b2], gf_ = gl[(cc * 4 + 1) * 8 + b2];
      float gg = gl[(cc * 4 + 2) * 8 + b2], go = gl[(cc * 4 + 3) * 8 + b2];
      float c2 = sig_(gf_) * creg + sig_(gi) * tanhf(gg);
      float hv = sig_(go) * tanhf(c2);
      creg = c2;
      cStore(myHist + (size_t)(t + 1) * 4096 + b2 * 512 + c0 + cc, hv);
      if (t == 511) {
        (L ? P.h1f : P.h0f)[b2 * 512 + c0 + cc] = hv;
        if (L) P.c1f[b2 * 512 + c0 + cc] = c2;
      }
    }
    __syncthreads();
  }
}

__global__ __launch_bounds__(256, 1) void enc_kernel(EncP P) {
  __shared__ float xcat0[8 * 772];
  __shared__ float xcat1[8 * 1028];
  __shared__ volatile int hstop;
  if (blockIdx.x >= 256) {
    // ---- heater: pure-register FMA spin; exits when all real WGs done ----
    if (threadIdx.x == 0) hstop = 0;
    __syncthreads();
    float d0 = 1.0f, d1 = 1.0001f, d2 = 0.9999f, d3 = 1.00005f;
    while (!hstop) {
#pragma unroll
      for (int z = 0; z < 64; ++z) {
        d0 = fmaf(d0, 1.0000001f, 1e-30f);
        d1 = fmaf(d1, 0.9999999f, 1e-30f);
        d2 = fmaf(d2, 1.0000002f, 1e-30f);
        d3 = fmaf(d3, 0.9999998f, 1e-30f);
      }
      if (threadIdx.x == 0 && cLoadI(P.done) >= 256) hstop = 1;
    }
    asm volatile("" :: "v"(d0), "v"(d1), "v"(d2), "v"(d3));
    return;
  }
  __builtin_amdgcn_s_setprio(1);   // real waves win issue arbitration
  if (blockIdx.x >> 7) enc_run<512>(P, xcat1, blockIdx.x, threadIdx.x);
  else enc_run<256>(P, xcat0, blockIdx.x, threadIdx.x);
  __syncthreads();
  if (threadIdx.x == 0)
    __hip_atomic_fetch_add(P.done, 1, __ATOMIC_RELAXED, SCOPE_AGENT);
}

// ---------------------------------------------------------------------------
// prep: k_enc/v_enc projections, decoder state init
// ---------------------------------------------------------------------------
__global__ __launch_bounds__(256) void prep_kernel(
    const float* Wk, const float* bk, const float* Wv, const float* bv,
    const float* h0f, const float* h1f, const float* c1f,
    float* kenc, float* venc, float* nhb, float* ncb) {
  const int w = blockIdx.x, tid = threadIdx.x;
  if (w < 64) {
    const int o = w * 256 + tid;
    const int kv = o >> 13, l = (o >> 12) & 1, b = (o >> 9) & 7, c = o & 511;
    const float4* h4 = (const float4*)((l ? h1f : h0f) + b * 512);
    const float4* w4 = (const float4*)((kv ? Wv : Wk) + (size_t)c * 512);
    float s0 = 0.f, s1 = 0.f, s2 = 0.f, s3 = 0.f;
#pragma unroll 8
    for (int k = 0; k < 128; ++k) {
      float4 a = w4[k], x = h4[k];
      s0 = fmaf(a.x, x.x, s0); s1 = fmaf(a.y, x.y, s1);
      s2 = fmaf(a.z, x.z, s2); s3 = fmaf(a.w, x.w, s3);
    }
    (kv ? venc : kenc)[l * 4096 + b * 512 + c] =
        (kv ? bv : bk)[c] + ((s0 + s1) + (s2 + s3));
  } else {
    const int o = (w - 64) * 256 + tid;
    nhb[16384 + o] = h1f[o & 4095];
    ncb[16384 + o] = c1f[o & 4095];
  }
}

// ---------------------------------------------------------------------------
// prep2: attention algebra folds (R3-verified).
// ---------------------------------------------------------------------------
__global__ __launch_bounds__(256) void prep2_kernel(
    const float* Wq, const float* Wk, const float* Wv, const float* Wo,
    const float* bq, const float* bk, const float* bv,
    const float* kenc, const float* venc,
    float* At, float* W2, float* u, float* pvec, float* veWo, float* bvo,
    float* sl0, float* sbb) {
  const int w = blockIdx.x, tid = threadIdx.x;
#pragma unroll 1
  for (int sub = 0; sub < 2; ++sub) {
    const int d = 2 * w + sub;
    for (int cc = 0; cc < 2; ++cc) {
      const int c = tid + cc * 256;
      float s0 = 0.f, s1 = 0.f, s2 = 0.f, s3 = 0.f;
      for (int i = 0; i < 512; i += 4) {
        s0 = fmaf(Wk[(i + 0) * 512 + d], Wq[(i + 0) * 512 + c], s0);
        s1 = fmaf(Wk[(i + 1) * 512 + d], Wq[(i + 1) * 512 + c], s1);
        s2 = fmaf(Wk[(i + 2) * 512 + d], Wq[(i + 2) * 512 + c], s2);
        s3 = fmaf(Wk[(i + 3) * 512 + d], Wq[(i + 3) * 512 + c], s3);
      }
      At[(size_t)d * 512 + c] = (s0 + s1) + (s2 + s3);
    }
    for (int cc = 0; cc < 2; ++cc) {
      const int dc = tid + cc * 256;
      float s0 = 0.f, s1 = 0.f, s2 = 0.f, s3 = 0.f;
      const float* wor = Wo + (size_t)d * 512;
      for (int c2 = 0; c2 < 512; c2 += 4) {
        s0 = fmaf(wor[c2 + 0], Wv[(size_t)(c2 + 0) * 512 + dc], s0);
        s1 = fmaf(wor[c2 + 1], Wv[(size_t)(c2 + 1) * 512 + dc], s1);
        s2 = fmaf(wor[c2 + 2], Wv[(size_t)(c2 + 2) * 512 + dc], s2);
        s3 = fmaf(wor[c2 + 3], Wv[(size_t)(c2 + 3) * 512 + dc], s3);
      }
      W2[(size_t)d * 512 + dc] = (s0 + s1) + (s2 + s3);
    }
  }
  if (w == 0) {
    for (int cc = 0; cc < 2; ++cc) {
      const int c = tid + cc * 256;
      float a = 0.f;
      for (int i = 0; i < 512; ++i)
        a += Wq[i * 512 + c] * bk[i] + Wk[i * 512 + c] * bq[i];
      u[c] = a;
    }
  } else if (w <= 32) {
    const int idx = (w - 1) * 256 + tid;
    const int l = idx >> 12, b = (idx >> 9) & 7, c = idx & 511;
    const float* ke = kenc + l * 4096 + b * 512;
    float a = 0.f;
    for (int i = 0; i < 512; ++i) a = fmaf(Wq[i * 512 + c], ke[i], a);
    pvec[idx] = a;
  } else if (w <= 64) {
    const int idx = (w - 33) * 256 + tid;
    const int l = idx >> 12, b = (idx >> 9) & 7, j = idx & 511;
    const float* ve = venc + l * 4096 + b * 512;
    const float* wo = Wo + (size_t)j * 512;
    float a = 0.f;
    for (int c = 0; c < 512; ++c) a = fmaf(wo[c], ve[c], a);
    veWo[idx] = a;
  } else if (w == 65) {
    for (int cc = 0; cc < 2; ++cc) {
      const int j = tid + cc * 256;
      const float* wo = Wo + (size_t)j * 512;
      float a = 0.f;
      for (int c = 0; c < 512; ++c) a = fmaf(wo[c], bv[c], a);
      bvo[j] = a;
    }
  } else if (w == 66) {
    if (tid < 16) {
      const int l = tid >> 3, b = tid & 7;
      const float* ke = kenc + l * 4096 + b * 512;
      float a = 0.f;
      for (int i = 0; i < 512; ++i) a = fmaf(bq[i], ke[i], a);
      sl0[tid] = a;
    } else if (tid == 16) {
      float a = 0.f;
      for (int i = 0; i < 512; ++i) a = fmaf(bq[i], bk[i], a);
      sbb[0] = a;
    }
  }
}

// ---------------------------------------------------------------------------
// prep3: fold static attention terms through Wout via LDS row-tiles.
// ---------------------------------------------------------------------------
__global__ __launch_bounds__(256) void prep3_kernel(
    const float* Wout, const float* bout, const float* bo, const float* veWo,
    float* E0g, float* E1g, float* bcg) {
  __shared__ float sv[16 * 516 + 512];
  __shared__ float stg[8 * 516];
  const int w = blockIdx.x, tid = threadIdx.x;
  for (int e = tid; e < 8704; e += 256) {
    if (e < 8192) sv[(e >> 9) * 516 + (e & 511)] = veWo[e];
    else sv[16 * 516 + (e - 8192)] = bo[e - 8192];
  }
  const int cbase = w * 125;
  for (int tile = 0; tile < 16; ++tile) {
    const int r0 = tile * 8;
    __syncthreads();
    for (int e = tid; e < 1024; e += 256) {
      const int rr = e >> 7, k4 = e & 127;
      int row = r0 + rr; if (row > 124) row = 124;
      *(float4*)&stg[rr * 516 + k4 * 4] =
          *(const float4*)&Wout[(size_t)(cbase + row) * 512 + k4 * 4];
    }
    __syncthreads();
    if (tid < 136) {
      const int rr = tid / 17, sel = tid - rr * 17;
      const int row = r0 + rr;
      if (row < 125) {
        const float4* a4 = (const float4*)&stg[rr * 516];
        const float4* x4 =
            (const float4*)&sv[sel < 16 ? sel * 516 : 16 * 516];
        float s0 = 0.f, s1 = 0.f, s2 = 0.f, s3 = 0.f;
#pragma unroll 8
        for (int k = 0; k < 128; ++k) {
          float4 a = a4[k], x = x4[k];
          s0 = fmaf(a.x, x.x, s0); s1 = fmaf(a.y, x.y, s1);
          s2 = fmaf(a.z, x.z, s2); s3 = fmaf(a.w, x.w, s3);
        }
        const float s = (s0 + s1) + (s2 + s3);
        const int c = cbase + row;
        if (sel < 16) (sel < 8 ? E0g : E1g)[(size_t)(sel & 7) * 32000 + c] = s;
        else bcg[c] = s + bout[c];
      }
    }
  }
}

// ---------------------------------------------------------------------------
// Decoder: 256 WGs x 256 thr, 12 steps x 3 one-hop barriers (R8, unchanged).
// ---------------------------------------------------------------------------
struct DecP {
  const float* emb;
  const float* Wih; const float* Whh; const float* bih; const float* bhh;
  const float* Wout;
  const float* At; const float* W2; const float* u; const float* bvo;
  const float* pvec; const float* sl0; const float* sbb;
  const float* E0g; const float* E1g; const float* bcg;
  float* nhb; float* ncb;  // [2][32][512]
  float* vbuf;             // [32][512]
  float* part_s;           // [3][32][64]
  ull* pvp;                // [256][32][4] packed (val,idx)
  int* obh;                // [12][4][8]
  int* res0;               // [13][8]
  __hip_bfloat16* hist;    // [12][32][32000]
  int* fl;
};

__global__ __launch_bounds__(256, 1) void dec_kernel(DecP P) {
  __shared__ float SM[29600];
  __shared__ float gl[2][4][32];
  __shared__ float slS[32][3];
  __shared__ float wslS[96];
  __shared__ float svv[32][8][4];
  __shared__ int sii[32][8][4];
  __shared__ float rvS[32][4];
  __shared__ int rtS[32][4];
  __shared__ int resS[4][13][8];
  __shared__ int oblS[32];
  __shared__ int tokS[32];
  __shared__ float pscS[32][8];
  __shared__ float nhsS[32][8];

  const int w = blockIdx.x, tid = threadIdx.x;
  float* hs = SM;
  float* tileS = SM;
  float* vqS = SM + 16896;
  float* tvE = SM + 21120;
  int* tiE = (int*)(SM + 25344);
  int ph = 0;

  if (tid < 104) {
    for (int n = 0; n < 4; ++n) resS[n][tid >> 3][tid & 7] = 1;
  }

  auto do_select = [&](int tt) {
    {
      const int r = tid >> 3, ch = tid & 7;
      float m4[4] = {-FLT_MAX, -FLT_MAX, -FLT_MAX, -FLT_MAX};
      int mi[4] = {0x7fffffff, 0x7fffffff, 0x7fffffff, 0x7fffffff};
      for (int g = 0; g < 4; ++g) {
        ull pk[32];
#pragma unroll
        for (int z = 0; z < 32; ++z) {
          const int wg = ch * 32 + g * 8 + (z >> 2);
          pk[z] = cLoad64(P.pvp + wg * 128 + r * 4 + (z & 3));
        }
#pragma unroll
        for (int z = 0; z < 32; ++z)
          ins4(m4, mi, __uint_as_float((unsigned)(pk[z] >> 32)),
               (int)(unsigned)(pk[z] & 0xffffffffu));
      }
#pragma unroll
      for (int k = 0; k < 4; ++k) { svv[r][ch][k] = m4[k]; sii[r][ch][k] = mi[k]; }
    }
    __syncthreads();
    if (tid < 32) {
      float m4[4] = {-FLT_MAX, -FLT_MAX, -FLT_MAX, -FLT_MAX};
      int mi[4] = {0x7fffffff, 0x7fffffff, 0x7fffffff, 0x7fffffff};
      for (int g2 = 0; g2 < 8; ++g2)
#pragma unroll
        for (int k = 0; k < 4; ++k) ins4(m4, mi, svv[tid][g2][k], sii[tid][g2][k]);
#pragma unroll
      for (int k = 0; k < 4; ++k) { rvS[tid][k] = m4[k]; rtS[tid][k] = mi[k]; }
    }
    __syncthreads();
    if (tid < 8) {
      const int b2 = tid;
      unsigned used = 0;
      int obl_[4], tkl_[4];
#pragma unroll
      for (int sel = 0; sel < 4; ++sel) {
        float bestv = -FLT_MAX; int bestj = -1;
        for (int j = 0; j < 16; ++j) {
          if (used & (1u << j)) continue;
          float vv = rvS[(j >> 2) * 8 + b2][j & 3];
          if (vv > bestv) { bestv = vv; bestj = j; }
        }
        used |= 1u << bestj;
        const int obn = bestj >> 2;
        obl_[sel] = obn;
        tkl_[sel] = rtS[obn * 8 + b2][bestj & 3];
        oblS[sel * 8 + b2] = obn;
        tokS[sel * 8 + b2] = tkl_[sel];
        if (w == 0) P.obh[tt * 32 + sel * 8 + b2] = obn;
      }
      if (w == 0) {
        int tmp[4][13];
        for (int n2 = 0; n2 < 4; ++n2)
          for (int s2 = 0; s2 < 13; ++s2) tmp[n2][s2] = resS[obl_[n2]][s2][b2];
        for (int n2 = 0; n2 < 4; ++n2)
          for (int s2 = 0; s2 < 13; ++s2) resS[n2][s2][b2] = tmp[n2][s2];
        for (int n2 = 0; n2 < 4; ++n2) resS[n2][tt + 1][b2] = tkl_[n2];
      }
    }
    __syncthreads();
    if (tt == 11 && w == 0 && tid < 104)
      P.res0[tid] = resS[0][tid >> 3][tid & 7];
  };

  for (int t = 0; t < 12; ++t) {
    const int curOff = (t & 1) * 16384, prevOff = ((t + 1) & 1) * 16384;

    if (t == 0) {
      __syncthreads();
      if (tid < 32) { oblS[tid] = tid >> 3; tokS[tid] = 1; }
      __syncthreads();
    } else {
      do_select(t - 1);
    }
    // ===== A: LSTM gates + cell with backpointer gather =====
    {
      const int col_l = tid >> 7, gate = (tid >> 5) & 3, nb = tid & 31;
      const int col = 2 * w + col_l;
      const int row = gate * 512 + col;
      for (int e = tid; e < 2048; e += 256) {
        const int nb2 = e >> 6, kf = e & 63;
        float4 v = *((const float4*)(P.emb + (size_t)tokS[nb2] * 256) + kf);
        *((float4*)hs + nb2 * 65 + kf) = v;
      }
      __syncthreads();
      float s0 = 0.f, s1 = 0.f, s2 = 0.f, s3 = 0.f;
      {
        const float4* a4 = (const float4*)(P.Wih + (size_t)row * 256);
        const float4* x4 = (const float4*)hs + nb * 65;
#pragma unroll 8
        for (int k = 0; k < 64; ++k) {
          float4 a = a4[k], x = x4[k];
          s0 = fmaf(a.x, x.x, s0); s1 = fmaf(a.y, x.y, s1);
          s2 = fmaf(a.z, x.z, s2); s3 = fmaf(a.w, x.w, s3);
        }
      }
      float acc = P.bih[row] + P.bhh[row];
      const ull* hsrc = (const ull*)(P.nhb + prevOff);
      const float4* w4row = (const float4*)(P.Whh + (size_t)row * 512);
      for (int ck = 0; ck < 2; ++ck) {
        __syncthreads();
        for (int e = tid; e < 4096; e += 256) {
          const int nb2 = e >> 7, k2 = e & 127;
          const int srow = oblS[nb2] * 8 + (nb2 & 7);
          ull v = cLoad64(hsrc + srow * 256 + ck * 128 + k2);
          *(ull*)(hs + nb2 * 260 + 2 * k2) = v;
        }
        __syncthreads();
        const float4* h4 = (const float4*)hs + nb * 65;
        const float4* w4 = w4row + ck * 64;
#pragma unroll 8
        for (int k = 0; k < 64; ++k) {
          float4 a = w4[k], x = h4[k];
          s0 = fmaf(a.x, x.x, s0); s1 = fmaf(a.y, x.y, s1);
          s2 = fmaf(a.z, x.z, s2); s3 = fmaf(a.w, x.w, s3);
        }
      }
      acc += (s0 + s1) + (s2 + s3);
      gl[col_l][gate][nb] = acc;
      __syncthreads();
      if (tid < 64) {
        const int cc = tid >> 5, nb2 = tid & 31;
        const int col2 = 2 * w + cc;
        float gi = gl[cc][0][nb2], gf_ = gl[cc][1][nb2];
        float gg = gl[cc][2][nb2], go = gl[cc][3][nb2];
        const int srow = oblS[nb2] * 8 + (nb2 & 7);
        float cold = cLoad(P.ncb + prevOff + srow * 512 + col2);
        float c2 = sig_(gf_) * cold + sig_(gi) * tanhf(gg);
        float hv = sig_(go) * tanhf(c2);
        cStore(P.nhb + curOff + nb2 * 512 + col2, hv);
        cStore(P.ncb + curOff + nb2 * 512 + col2, c2);
      }
    }
    fbar1(P.fl, ++ph);

    // ===== B: p=0 -> score partials (At fold); p=1 -> vbuf (W2 fold) =====
    if (w < 128) {
      const int p = w >> 6, cb = w & 63;
      const int col_l = tid >> 5, nb = tid & 31;
      const int col = cb * 8 + col_l;
      const float* W = (p ? P.W2 : P.At) + (size_t)col * 512;
      float acc = (p ? P.bvo : P.u)[col];
      {
        const float4* w4row = (const float4*)W;
        float s0 = 0.f, s1 = 0.f, s2 = 0.f, s3 = 0.f;
        for (int ck = 0; ck < 2; ++ck) {
          __syncthreads();
          const ull* s8 = (const ull*)(P.nhb + curOff);
          for (int e = tid; e < 4096; e += 256) {
            const int nb2 = e >> 7, k2 = e & 127;
            ull v = cLoad64(s8 + nb2 * 256 + ck * 128 + k2);
            *(ull*)(hs + nb2 * 260 + 2 * k2) = v;
          }
          __syncthreads();
          const float4* h4 = (const float4*)hs + nb * 65;
          const float4* w4 = w4row + ck * 64;
#pragma unroll 8
          for (int k = 0; k < 64; ++k) {
            float4 a = w4[k], x = h4[k];
            s0 = fmaf(a.x, x.x, s0); s1 = fmaf(a.y, x.y, s1);
            s2 = fmaf(a.z, x.z, s2); s3 = fmaf(a.w, x.w, s3);
          }
        }
        acc += (s0 + s1) + (s2 + s3);
      }
      if (p) {
        cStore(P.vbuf + nb * 512 + col, acc);
      } else {
        const float nhv = cLoad(P.nhb + curOff + nb * 512 + col);
        pscS[nb][col_l] = nhv * acc;
        nhsS[nb][col_l] = nhv;
        __syncthreads();
        if (tid < 32) {
          const int nb2 = tid, b = nb2 & 7;
          float s2a = 0.f, l0 = 0.f, l1 = 0.f;
#pragma unroll
          for (int i2 = 0; i2 < 8; ++i2) {
            s2a += pscS[nb2][i2];
            const float nv = nhsS[nb2][i2];
            l0 = fmaf(nv, P.pvec[b * 512 + cb * 8 + i2], l0);
            l1 = fmaf(nv, P.pvec[4096 + b * 512 + cb * 8 + i2], l1);
          }
          cStore(P.part_s + (0 * 32 + nb2) * 64 + cb, l0);
          cStore(P.part_s + (1 * 32 + nb2) * 64 + cb, l1);
          cStore(P.part_s + (2 * 32 + nb2) * 64 + cb, s2a);
        }
      }
    }
    fbar1(P.fl, ++ph);

    // ===== E: softmax (from partials) + logits via LDS-tiled Wout + top-4 ==
    {
      const int cbase = w * 125;
      if (tid < 96) {
        const int nb = tid / 3, l = tid - (tid / 3) * 3, b = nb & 7;
        const ull* ps = (const ull*)(P.part_s + (l * 32 + nb) * 64);
        ull pk[32];
#pragma unroll
        for (int z = 0; z < 32; ++z) pk[z] = cLoad64(ps + z);
        float s = 0.f;
#pragma unroll
        for (int z = 0; z < 32; ++z) { float2 f = u2f2(pk[z]); s += f.x + f.y; }
        const float bias = (l < 2) ? P.sl0[l * 8 + b] : P.sbb[0];
        slS[nb][l] = (s + bias) * (1.0f / sqrtf(512.0f));
      }
      __syncthreads();
      if (tid < 32) {
        float a = slS[tid][0], b2 = slS[tid][1], c3 = slS[tid][2];
        float m = fmaxf(a, fmaxf(b2, c3));
        float e0 = expf(a - m), e1 = expf(b2 - m), e2 = expf(c3 - m);
        float inv = 1.0f / (e0 + e1 + e2);
        wslS[tid * 3 + 0] = e0 * inv;
        wslS[tid * 3 + 1] = e1 * inv;
        wslS[tid * 3 + 2] = e2 * inv;
      }
      const int rg = tid >> 3, ng = tid & 7;
      float acc[4][4];
#pragma unroll
      for (int i = 0; i < 4; ++i)
#pragma unroll
        for (int j = 0; j < 4; ++j) acc[i][j] = 0.f;
      for (int q = 0; q < 4; ++q) {
        __syncthreads();
        for (int e = tid; e < 1024; e += 256) {
          const int nb = e >> 5, kf = e & 31;
          ull u0 = cLoad64((const ull*)(P.vbuf + nb * 512 + q * 128 + kf * 4));
          ull u1 = cLoad64((const ull*)(P.vbuf + nb * 512 + q * 128 + kf * 4 + 2));
          float2 a = u2f2(u0), b2 = u2f2(u1);
          float4 v = {a.x, a.y, b2.x, b2.y};
          *(float4*)(vqS + (nb & 3) * 1056 + (nb >> 2) * 132 + kf * 4) = v;
        }
        for (int it = 0; it < 16; ++it) {
          const int idx = it * 256 + tid;
          if (idx < 4000) {
            const int r = idx >> 5, kf = idx & 31;
            float4 v = *(const float4*)(P.Wout + (size_t)(cbase + r) * 512 +
                                        q * 128 + kf * 4);
            *(float4*)(tileS + (r & 3) * 4224 + (r >> 2) * 132 + kf * 4) = v;
          }
        }
        __syncthreads();
        for (int kf = 0; kf < 32; ++kf) {
          float4 xv[4], wv[4];
#pragma unroll
          for (int j = 0; j < 4; ++j)
            xv[j] = *(const float4*)(vqS + j * 1056 + ng * 132 + kf * 4);
#pragma unroll
          for (int i = 0; i < 4; ++i)
            wv[i] = *(const float4*)(tileS + i * 4224 + rg * 132 + kf * 4);
#pragma unroll
          for (int i = 0; i < 4; ++i)
#pragma unroll
            for (int j = 0; j < 4; ++j) {
              float a = acc[i][j];
              a = fmaf(wv[i].x, xv[j].x, a); a = fmaf(wv[i].y, xv[j].y, a);
              a = fmaf(wv[i].z, xv[j].z, a); a = fmaf(wv[i].w, xv[j].w, a);
              acc[i][j] = a;
            }
        }
      }
      __syncthreads();
      float w0w[4], w1w[4], w2w[4];
#pragma unroll
      for (int j = 0; j < 4; ++j) {
        const int nb = ng * 4 + j;
        w0w[j] = wslS[nb * 3 + 0]; w1w[j] = wslS[nb * 3 + 1]; w2w[j] = wslS[nb * 3 + 2];
      }
      float v4[4][4]; int i4[4][4];
#pragma unroll
      for (int j = 0; j < 4; ++j)
#pragma unroll
        for (int k = 0; k < 4; ++k) { v4[j][k] = -FLT_MAX; i4[j][k] = 0x7fffffff; }
#pragma unroll
      for (int i = 0; i < 4; ++i) {
        const int r = rg * 4 + i;
        if (r < 125) {
          const int c = cbase + r;
          const float bcv = P.bcg[c];
#pragma unroll
          for (int j = 0; j < 4; ++j) {
            const int nb = ng * 4 + j, b = nb & 7;
            const float e0 = P.E0g[(size_t)b * 32000 + c];
            const float e1 = P.E1g[(size_t)b * 32000 + c];
            const float L = fmaf(w2w[j], acc[i][j],
                                 fmaf(w0w[j], e0, fmaf(w1w[j], e1, bcv)));
            P.hist[(size_t)t * 1024000 + (size_t)nb * 32000 + c] = __float2bfloat16(L);
            ins4(v4[j], i4[j], L, c);
          }
        }
      }
#pragma unroll
      for (int j = 0; j < 4; ++j)
#pragma unroll
        for (int k = 0; k < 4; ++k) {
          tvE[(ng * 4 + j) * 132 + rg * 4 + k] = v4[j][k];
          tiE[(ng * 4 + j) * 132 + rg * 4 + k] = i4[j][k];
        }
      __syncthreads();
      if (tid < 32) {
        float m4[4] = {-FLT_MAX, -FLT_MAX, -FLT_MAX, -FLT_MAX};
        int mi[4] = {0x7fffffff, 0x7fffffff, 0x7fffffff, 0x7fffffff};
        for (int e = 0; e < 128; ++e)
          ins4(m4, mi, tvE[tid * 132 + e], tiE[tid * 132 + e]);
#pragma unroll
        for (int k = 0; k < 4; ++k) {
          ull pk = ((ull)__float_as_uint(m4[k]) << 32) | (unsigned)mi[k];
          cStore64(P.pvp + w * 128 + tid * 4 + k, pk);
        }
      }
    }
    fbar1(P.fl, ++ph);
  }
  if (w == 0) do_select(11);
}

// ---------------------------------------------------------------------------
// Output assembly (unchanged).
// ---------------------------------------------------------------------------
__global__ __launch_bounds__(256) void out_kernel(const __hip_bfloat16* hist,
                                                  const int* obh, const int* res0,
                                                  float* out) {
  __shared__ float sh[13 * 1000];
  __shared__ int sbArr[12];
  const int w = blockIdx.x, tid = threadIdx.x;
  const int b = w >> 5, v0 = (w & 31) * 1000;
  if (tid == 0) {
    int beta = 0;
    for (int t = 11; t >= 0; --t) {
      const int sb = obh[t * 32 + beta * 8 + b];
      sbArr[t] = sb;
      beta = sb;
    }
  }
  __syncthreads();
  for (int e = tid; e < 12000; e += 256) {
    const int t = e / 1000, vv = e - t * 1000;
    sh[(t + 1) * 1000 + vv] = __bfloat162float(
        hist[(size_t)(t * 32 + sbArr[t] * 8 + b) * 32000 + v0 + vv]);
  }
  for (int e = tid; e < 1000; e += 256) sh[e] = (v0 + e == 1) ? 1.0f : 0.0f;
  __syncthreads();
  float* base = out + 104 + (size_t)(b * 32000 + v0) * 13;
  for (int o = tid; o < 13000; o += 256) {
    const int v = o / 13, t = o - v * 13;
    base[o] = sh[t * 1000 + v];
  }
  if (w == 0 && tid < 104) {
    out[(tid & 7) * 13 + (tid >> 3)] = (float)res0[tid];
  }
}

// ---------------------------------------------------------------------------
extern "C" void kernel_launch(void* const* d_in, const int* in_sizes, int n_in,
                              void* d_out, int out_size, void* d_ws, size_t ws_size,
                              hipStream_t stream) {
  const int* text  = (const int*)d_in[0];
  const float* embE = (const float*)d_in[1];
  const float* embD = (const float*)d_in[2];
  const float* Wih0 = (const float*)d_in[3];
  const float* Whh0 = (const float*)d_in[4];
  const float* bih0 = (const float*)d_in[5];
  const float* bhh0 = (const float*)d_in[6];
  const float* Wih1 = (const float*)d_in[7];
  const float* Whh1 = (const float*)d_in[8];
  const float* bih1 = (const float*)d_in[9];
  const float* bhh1 = (const float*)d_in[10];
  const float* dWih = (const float*)d_in[11];
  const float* dWhh = (const float*)d_in[12];
  const float* dbih = (const float*)d_in[13];
  const float* dbhh = (const float*)d_in[14];
  const float* Wq = (const float*)d_in[15];
  const float* bq = (const float*)d_in[16];
  const float* Wk = (const float*)d_in[17];
  const float* bk = (const float*)d_in[18];
  const float* Wv = (const float*)d_in[19];
  const float* bv = (const float*)d_in[20];
  const float* Wo = (const float*)d_in[21];
  const float* bo = (const float*)d_in[22];
  const float* Wout = (const float*)d_in[23];
  const float* bout = (const float*)d_in[24];

  char* ws = (char*)d_ws;
  size_t off = 0;
  auto alloc = [&](size_t bytes) -> char* {
    off = (off + 511) & ~(size_t)511;
    char* p = ws + off;
    off += bytes;
    return p;
  };
  float* h0hist = (float*)alloc((size_t)513 * 4096 * 4);  // 8.4 MB
  float* h1hist = (float*)alloc((size_t)513 * 4096 * 4);  // 8.4 MB
  int* decFl  = (int*)alloc((size_t)262144 * 4);          // [256][32] lines
  int* doneE  = (int*)alloc(32 * 4);
  float* h0f  = (float*)alloc(4096 * 4);
  float* h1f  = (float*)alloc(4096 * 4);
  float* c1f  = (float*)alloc(4096 * 4);
  float* kenc = (float*)alloc(8192 * 4);
  float* venc = (float*)alloc(8192 * 4);
  float* At   = (float*)alloc((size_t)262144 * 4);
  float* W2   = (float*)alloc((size_t)262144 * 4);
  float* u    = (float*)alloc(512 * 4);
  float* pvec = (float*)alloc(8192 * 4);
  float* veWo = (float*)alloc(8192 * 4);
  float* bvo  = (float*)alloc(512 * 4);
  float* sl0  = (float*)alloc(16 * 4);
  float* sbb  = (float*)alloc(32 * 4);
  float* E0g  = (float*)alloc((size_t)256000 * 4);
  float* E1g  = (float*)alloc((size_t)256000 * 4);
  float* bcg  = (float*)alloc(32000 * 4);
  float* nhb  = (float*)alloc(2 * 16384 * 4);
  float* ncb  = (float*)alloc(2 * 16384 * 4);
  float* vbuf = (float*)alloc(16384 * 4);
  float* part_s = (float*)alloc(6144 * 4);
  ull* pvp    = (ull*)alloc((size_t)32768 * 8);
  int* obh    = (int*)alloc(384 * 4);
  int* res0   = (int*)alloc(104 * 4);
  __hip_bfloat16* hist = (__hip_bfloat16*)alloc((size_t)12288000 * 2);
  if (off > ws_size) return;  // ~49 MB required

  // sentinel-fill the dataflow buffers (0xFF bytes -> -NaN per float lane)
  hipMemsetAsync(h0hist, 0xFF, (size_t)513 * 4096 * 4, stream);
  hipMemsetAsync(h1hist, 0xFF, (size_t)513 * 4096 * 4, stream);
  hipMemsetAsync(decFl, 0, (size_t)262144 * 4, stream);
  hipMemsetAsync(doneE, 0, 32 * 4, stream);

  EncP ep{text, embE, Wih0, Whh0, bih0, bhh0, Wih1, Whh1, bih1, bhh1,
          h0hist, h1hist, h0f, h1f, c1f, doneE};
  enc_kernel<<<512, 256, 0, stream>>>(ep);

  prep_kernel<<<128, 256, 0, stream>>>(Wk, bk, Wv, bv, h0f, h1f, c1f, kenc, venc,
                                       nhb, ncb);
  prep2_kernel<<<256, 256, 0, stream>>>(Wq, Wk, Wv, Wo, bq, bk, bv, kenc, venc,
                                        At, W2, u, pvec, veWo, bvo, sl0, sbb);
  prep3_kernel<<<256, 256, 0, stream>>>(Wout, bout, bo, veWo, E0g, E1g, bcg);

  DecP dp{embD, dWih, dWhh, dbih, dbhh, Wout,
          At, W2, u, bvo, pvec, sl0, sbb, E0g, E1g, bcg,
          nhb, ncb, vbuf, part_s, pvp, obh, res0, hist, decFl};
  dec_kernel<<<256, 256, 0, stream>>>(dp);

  out_kernel<<<256, 256, 0, stream>>>(hist, obh, res0, (float*)d_out);
}

// Round 13
// 5812.460 us; speedup vs baseline: 1.3203x; 1.0791x over previous
//
#include <hip/hip_runtime.h>
#include <hip/hip_bf16.h>
#include <float.h>

// ---------------------------------------------------------------------------
// Beam-search seq2seq (2-layer LSTM encoder S=512, 4-beam decoder MAXLEN=12,
// V=32000). fp32 math; bf16 only for stored logits history.
//
// R13 = R10 encoder (zero-flag write-once dataflow + batched sentinel
// polling; measured-best) + WING OVERLAP: WGs 256..511 co-reside with the
// encoder and compute the encoder-INDEPENDENT prep work (At=Wk^T Wq,
// W2=Wo*Wv, u, bvo, sbb, bcg=bo*Wout+bout) then exit. R12 measured the
// co-residency penalty at ~5% while the wing runs; the wing removes
// ~300-400us of serial post-encoder prep (and bcg's Wout sweep pre-warms
// the LLC for the decoder). Post-enc: prep (kenc/venc/state), prep2b
// (pvec/veWo/sl0), prep3 (E0g/E1g). Decoder/out unchanged (R8 structure).
// ---------------------------------------------------------------------------

using ull = unsigned long long;

#define SCOPE_AGENT __HIP_MEMORY_SCOPE_AGENT

__device__ __forceinline__ float cLoad(const float* p) {
  return __hip_atomic_load(p, __ATOMIC_RELAXED, SCOPE_AGENT);
}
__device__ __forceinline__ void cStore(float* p, float v) {
  __hip_atomic_store(p, v, __ATOMIC_RELAXED, SCOPE_AGENT);
}
__device__ __forceinline__ int cLoadI(const int* p) {
  return __hip_atomic_load(p, __ATOMIC_RELAXED, SCOPE_AGENT);
}
__device__ __forceinline__ void cStoreI(int* p, int v) {
  __hip_atomic_store(p, v, __ATOMIC_RELAXED, SCOPE_AGENT);
}
__device__ __forceinline__ ull cLoad64(const ull* p) {
  return __hip_atomic_load(p, __ATOMIC_RELAXED, SCOPE_AGENT);
}
__device__ __forceinline__ void cStore64(ull* p, ull v) {
  __hip_atomic_store(p, v, __ATOMIC_RELAXED, SCOPE_AGENT);
}

__device__ __forceinline__ float2 u2f2(ull u) {
  union { ull u; float2 f; } c; c.u = u; return c.f;
}

__device__ __forceinline__ bool isSent(ull v) {
  return (unsigned)v == 0xFFFFFFFFu || (unsigned)(v >> 32) == 0xFFFFFFFFu;
}

// One-hop replicated-flag barrier for the decoder (R7/R8, unchanged).
__device__ __forceinline__ void fbar1(int* fl, int phase) {
  __syncthreads();
  if (threadIdx.x < 32)
    cStoreI(fl + (blockIdx.x * 32 + threadIdx.x) * 32, phase);
  {
    const int* f = fl + (threadIdx.x * 32 + (blockIdx.x >> 3)) * 32;
    while (cLoadI(f) < phase) {}
  }
  __syncthreads();
}

__device__ __forceinline__ float sig_(float x) { return 1.0f / (1.0f + expf(-x)); }

// top-4 sorted insert; ordering matches lax.top_k (desc value, tie -> lower idx)
__device__ __forceinline__ void ins4(float* v, int* id, float nv, int ni) {
  if (nv > v[3] || (nv == v[3] && ni < id[3])) {
    v[3] = nv; id[3] = ni;
#pragma unroll
    for (int p = 3; p > 0; --p) {
      bool sw = (v[p] > v[p - 1]) || (v[p] == v[p - 1] && id[p] < id[p - 1]);
      if (sw) {
        float t0 = v[p]; v[p] = v[p - 1]; v[p - 1] = t0;
        int t1 = id[p]; id[p] = id[p - 1]; id[p - 1] = t1;
      }
    }
  }
}

// ---------------------------------------------------------------------------
// Encoder: 256 real WGs (R10 dataflow) + 256 wing WGs (independent prep).
// ---------------------------------------------------------------------------
struct EncP {
  const int* text; const float* emb;
  const float* Wih0; const float* Whh0; const float* bih0; const float* bhh0;
  const float* Wih1; const float* Whh1; const float* bih1; const float* bhh1;
  float* h0hist; float* h1hist;   // [513][4096] each, sentinel-initialized
  float* h0f; float* h1f; float* c1f;
  // wing inputs/outputs (encoder-independent prep):
  const float* Wq; const float* Wk; const float* Wv; const float* Wo;
  const float* bq; const float* bk; const float* bv; const float* bo;
  const float* Wout; const float* bout;
  float* At; float* W2; float* u; float* bvo; float* sbb; float* bcg;
};

template <int KX>
__device__ void enc_run(const EncP& P, float* xcat, int w, int tid) {
  constexpr int KTOT = KX + 512;
  constexpr int ST = KTOT + 4;       // per-batch stride (ST%32==4)
  constexpr int KSL = KTOT / 8;
  constexpr int Q = KSL / 4;
  constexpr int L = (KX == 512) ? 1 : 0;
  __shared__ float part[16 * 8 * 8];
  __shared__ float gl[128];

  const int c0 = (w & 127) * 4;
  const int kh = tid >> 5, col = (tid >> 3) & 3, b = tid & 7;
  const int kbase = kh * KSL;

  const float* Wih = L ? P.Wih1 : P.Wih0;
  const float* Whh = L ? P.Whh1 : P.Whh0;
  const float4* wih4[4]; const float4* whh4[4];
#pragma unroll
  for (int g = 0; g < 4; ++g) {
    const int row = g * 512 + c0 + col;
    wih4[g] = (const float4*)(Wih + (size_t)row * KX);
    whh4[g] = (const float4*)(Whh + (size_t)row * 512);
  }
  float bsum = 0.f;
  if (tid < 128) {
    const int r = tid >> 3;
    const int row = (r & 3) * 512 + c0 + (r >> 2);
    bsum = (L ? P.bih1[row] + P.bhh1[row] : P.bih0[row] + P.bhh0[row]);
  }
  float creg = 0.f;
  float* myHist = L ? P.h1hist : P.h0hist;

  int qx = (KX - kbase) / 4;
  qx = qx < 0 ? 0 : (qx > Q ? Q : qx);

  // pre-zero the h-part of xcat (used at t=0 where h_{-1}=0)
  for (int e = tid; e < 4096; e += 256)
    xcat[(e >> 9) * ST + KX + (e & 511)] = 0.f;
  __syncthreads();

  for (int t = 0; t < 512; ++t) {
    // ---- stage inputs (batched parallel loads + straggler re-poll) ----
    if constexpr (KX == 256) {
      for (int e = tid; e < 1024; e += 256) {
        const int b2 = e >> 7, k2 = e & 127;
        const int tokv = P.text[t * 8 + b2];
        *(float2*)(xcat + b2 * ST + 2 * k2) =
            *(const float2*)(P.emb + (size_t)tokv * 256 + 2 * k2);
      }
      if (t >= 1) {
        const ull* hq = (const ull*)(myHist + (size_t)t * 4096) + tid;
        ull v[8];
#pragma unroll
        for (int z = 0; z < 8; ++z) v[z] = cLoad64(hq + z * 256);
        for (;;) {
          bool any = false;
#pragma unroll
          for (int z = 0; z < 8; ++z)
            if (isSent(v[z])) { v[z] = cLoad64(hq + z * 256); any = true; }
          if (!any) break;
        }
#pragma unroll
        for (int z = 0; z < 8; ++z)
          *(ull*)(xcat + z * ST + KX + 2 * tid) = v[z];
      }
    } else {
      const ull* xq0 = (const ull*)(P.h0hist + (size_t)(t + 1) * 4096) + tid;
      const ull* hq = (const ull*)(P.h1hist + (size_t)t * 4096) + tid;
      ull vx[8], vh[8];
#pragma unroll
      for (int z = 0; z < 8; ++z) vx[z] = cLoad64(xq0 + z * 256);
      if (t >= 1) {
#pragma unroll
        for (int z = 0; z < 8; ++z) vh[z] = cLoad64(hq + z * 256);
      }
      for (;;) {
        bool any = false;
#pragma unroll
        for (int z = 0; z < 8; ++z)
          if (isSent(vx[z])) { vx[z] = cLoad64(xq0 + z * 256); any = true; }
        if (t >= 1) {
#pragma unroll
          for (int z = 0; z < 8; ++z)
            if (isSent(vh[z])) { vh[z] = cLoad64(hq + z * 256); any = true; }
        }
        if (!any) break;
      }
#pragma unroll
      for (int z = 0; z < 8; ++z)
        *(ull*)(xcat + z * ST + 2 * tid) = vx[z];
      if (t >= 1) {
#pragma unroll
        for (int z = 0; z < 8; ++z)
          *(ull*)(xcat + z * ST + KX + 2 * tid) = vh[z];
      }
    }
    __syncthreads();

    // ---- 4-gate dot over this thread's k-slice ----
    float a0 = 0.f, a1 = 0.f, a2 = 0.f, a3 = 0.f;
    {
      const float4* xq = (const float4*)(xcat + b * ST + kbase);
      const int iw = kbase >> 2, ih = (kbase - KX) >> 2;
#pragma unroll 4
      for (int q = 0; q < qx; ++q) {
        float4 x = xq[q];
        float4 w0 = wih4[0][iw + q], w1 = wih4[1][iw + q];
        float4 w2 = wih4[2][iw + q], w3 = wih4[3][iw + q];
        a0 = fmaf(w0.x, x.x, a0); a0 = fmaf(w0.y, x.y, a0);
        a0 = fmaf(w0.z, x.z, a0); a0 = fmaf(w0.w, x.w, a0);
        a1 = fmaf(w1.x, x.x, a1); a1 = fmaf(w1.y, x.y, a1);
        a1 = fmaf(w1.z, x.z, a1); a1 = fmaf(w1.w, x.w, a1);
        a2 = fmaf(w2.x, x.x, a2); a2 = fmaf(w2.y, x.y, a2);
        a2 = fmaf(w2.z, x.z, a2); a2 = fmaf(w2.w, x.w, a2);
        a3 = fmaf(w3.x, x.x, a3); a3 = fmaf(w3.y, x.y, a3);
        a3 = fmaf(w3.z, x.z, a3); a3 = fmaf(w3.w, x.w, a3);
      }
#pragma unroll 4
      for (int q = qx; q < Q; ++q) {
        float4 x = xq[q];
        float4 w0 = whh4[0][ih + q], w1 = whh4[1][ih + q];
        float4 w2 = whh4[2][ih + q], w3 = whh4[3][ih + q];
        a0 = fmaf(w0.x, x.x, a0); a0 = fmaf(w0.y, x.y, a0);
        a0 = fmaf(w0.z, x.z, a0); a0 = fmaf(w0.w, x.w, a0);
        a1 = fmaf(w1.x, x.x, a1); a1 = fmaf(w1.y, x.y, a1);
        a1 = fmaf(w1.z, x.z, a1); a1 = fmaf(w1.w, x.w, a1);
        a2 = fmaf(w2.x, x.x, a2); a2 = fmaf(w2.y, x.y, a2);
        a2 = fmaf(w2.z, x.z, a2); a2 = fmaf(w2.w, x.w, a2);
        a3 = fmaf(w3.x, x.x, a3); a3 = fmaf(w3.y, x.y, a3);
        a3 = fmaf(w3.z, x.z, a3); a3 = fmaf(w3.w, x.w, a3);
      }
    }
    part[((col * 4 + 0) * 8 + b) * 8 + kh] = a0;
    part[((col * 4 + 1) * 8 + b) * 8 + kh] = a1;
    part[((col * 4 + 2) * 8 + b) * 8 + kh] = a2;
    part[((col * 4 + 3) * 8 + b) * 8 + kh] = a3;
    __syncthreads();
    if (tid < 128) {
      const int r = tid >> 3, b2 = tid & 7;
      const float4* pp = (const float4*)(part + (r * 8 + b2) * 8);
      float4 p0 = pp[0], p1 = pp[1];
      gl[r * 8 + b2] =
          bsum + (((p0.x + p0.y) + (p0.z + p0.w)) + ((p1.x + p1.y) + (p1.z + p1.w)));
    }
    __syncthreads();
    if (tid < 32) {
      const int cc = tid >> 3, b2 = tid & 7;
      float gi = gl[(cc * 4 + 0) * 8 + b2], gf_ = gl[(cc * 4 + 1) * 8 + b2];
      float gg = gl[(cc * 4 + 2) * 8 + b2], go = gl[(cc * 4 + 3) * 8 + b2];
      float c2 = sig_(gf_) * creg + sig_(gi) * tanhf(gg);
      float hv = sig_(go) * tanhf(c2);
      creg = c2;
      cStore(myHist + (size_t)(t + 1) * 4096 + b2 * 512 + c0 + cc, hv);
      if (t == 511) {
        (L ? P.h1f : P.h0f)[b2 * 512 + c0 + cc] = hv;
        if (L) P.c1f[b2 * 512 + c0 + cc] = c2;
      }
    }
    __syncthreads();
  }
}

// Wing: encoder-independent prep (At, W2, u, bvo, sbb, bcg) under the enc.
__device__ void enc_wing(const EncP& P, int wgw, int tid) {
#pragma unroll 1
  for (int sub = 0; sub < 2; ++sub) {
    const int d = 2 * wgw + sub;
    for (int cc = 0; cc < 2; ++cc) {
      const int c = tid + cc * 256;
      float s0 = 0.f, s1 = 0.f, s2 = 0.f, s3 = 0.f;
      for (int i = 0; i < 512; i += 4) {
        s0 = fmaf(P.Wk[(i + 0) * 512 + d], P.Wq[(i + 0) * 512 + c], s0);
        s1 = fmaf(P.Wk[(i + 1) * 512 + d], P.Wq[(i + 1) * 512 + c], s1);
        s2 = fmaf(P.Wk[(i + 2) * 512 + d], P.Wq[(i + 2) * 512 + c], s2);
        s3 = fmaf(P.Wk[(i + 3) * 512 + d], P.Wq[(i + 3) * 512 + c], s3);
      }
      P.At[(size_t)d * 512 + c] = (s0 + s1) + (s2 + s3);
    }
    for (int cc = 0; cc < 2; ++cc) {
      const int dc = tid + cc * 256;
      float s0 = 0.f, s1 = 0.f, s2 = 0.f, s3 = 0.f;
      const float* wor = P.Wo + (size_t)d * 512;
      for (int c2 = 0; c2 < 512; c2 += 4) {
        s0 = fmaf(wor[c2 + 0], P.Wv[(size_t)(c2 + 0) * 512 + dc], s0);
        s1 = fmaf(wor[c2 + 1], P.Wv[(size_t)(c2 + 1) * 512 + dc], s1);
        s2 = fmaf(wor[c2 + 2], P.Wv[(size_t)(c2 + 2) * 512 + dc], s2);
        s3 = fmaf(wor[c2 + 3], P.Wv[(size_t)(c2 + 3) * 512 + dc], s3);
      }
      P.W2[(size_t)d * 512 + dc] = (s0 + s1) + (s2 + s3);
    }
  }
  // bcg rows [wgw*125, wgw*125+125): bcg[c] = bo . Wout[c] + bout[c]
  if (tid < 125) {
    const int c = wgw * 125 + tid;
    const float4* wr = (const float4*)(P.Wout + (size_t)c * 512);
    const float4* bo4 = (const float4*)P.bo;
    float s0 = 0.f, s1 = 0.f, s2 = 0.f, s3 = 0.f;
#pragma unroll 8
    for (int k = 0; k < 128; ++k) {
      float4 a = wr[k], x = bo4[k];
      s0 = fmaf(a.x, x.x, s0); s1 = fmaf(a.y, x.y, s1);
      s2 = fmaf(a.z, x.z, s2); s3 = fmaf(a.w, x.w, s3);
    }
    P.bcg[c] = (s0 + s1) + (s2 + s3) + P.bout[c];
  }
  if (wgw == 0) {
    for (int cc = 0; cc < 2; ++cc) {
      const int c = tid + cc * 256;
      float a = 0.f;
      for (int i = 0; i < 512; ++i)
        a += P.Wq[i * 512 + c] * P.bk[i] + P.Wk[i * 512 + c] * P.bq[i];
      P.u[c] = a;
    }
  } else if (wgw == 65) {
    for (int cc = 0; cc < 2; ++cc) {
      const int j = tid + cc * 256;
      const float* wo = P.Wo + (size_t)j * 512;
      float a = 0.f;
      for (int c = 0; c < 512; ++c) a = fmaf(wo[c], P.bv[c], a);
      P.bvo[j] = a;
    }
  } else if (wgw == 66) {
    if (tid == 0) {
      float a = 0.f;
      for (int i = 0; i < 512; ++i) a = fmaf(P.bq[i], P.bk[i], a);
      P.sbb[0] = a;
    }
  }
}

__global__ __launch_bounds__(256, 1) void enc_kernel(EncP P) {
  __shared__ float xcat0[8 * 772];
  __shared__ float xcat1[8 * 1028];
  if (blockIdx.x >= 256) {           // wing: independent prep, then exit
    enc_wing(P, blockIdx.x - 256, threadIdx.x);
    return;
  }
  __builtin_amdgcn_s_setprio(1);     // real waves win issue arbitration
  if (blockIdx.x >> 7) enc_run<512>(P, xcat1, blockIdx.x, threadIdx.x);
  else enc_run<256>(P, xcat0, blockIdx.x, threadIdx.x);
}

// ---------------------------------------------------------------------------
// prep: k_enc/v_enc projections, decoder state init
// ---------------------------------------------------------------------------
__global__ __launch_bounds__(256) void prep_kernel(
    const float* Wk, const float* bk, const float* Wv, const float* bv,
    const float* h0f, const float* h1f, const float* c1f,
    float* kenc, float* venc, float* nhb, float* ncb) {
  const int w = blockIdx.x, tid = threadIdx.x;
  if (w < 64) {
    const int o = w * 256 + tid;
    const int kv = o >> 13, l = (o >> 12) & 1, b = (o >> 9) & 7, c = o & 511;
    const float4* h4 = (const float4*)((l ? h1f : h0f) + b * 512);
    const float4* w4 = (const float4*)((kv ? Wv : Wk) + (size_t)c * 512);
    float s0 = 0.f, s1 = 0.f, s2 = 0.f, s3 = 0.f;
#pragma unroll 8
    for (int k = 0; k < 128; ++k) {
      float4 a = w4[k], x = h4[k];
      s0 = fmaf(a.x, x.x, s0); s1 = fmaf(a.y, x.y, s1);
      s2 = fmaf(a.z, x.z, s2); s3 = fmaf(a.w, x.w, s3);
    }
    (kv ? venc : kenc)[l * 4096 + b * 512 + c] =
        (kv ? bv : bk)[c] + ((s0 + s1) + (s2 + s3));
  } else {
    const int o = (w - 64) * 256 + tid;
    nhb[16384 + o] = h1f[o & 4095];
    ncb[16384 + o] = c1f[o & 4095];
  }
}

// ---------------------------------------------------------------------------
// prep2b: encoder-DEPENDENT attention folds only (pvec, veWo, sl0). Grid 65.
// ---------------------------------------------------------------------------
__global__ __launch_bounds__(256) void prep2b_kernel(
    const float* Wq, const float* Wo, const float* bq,
    const float* kenc, const float* venc,
    float* pvec, float* veWo, float* sl0) {
  const int w = blockIdx.x, tid = threadIdx.x;
  if (w < 32) {
    const int idx = w * 256 + tid;                // [l][b][c]
    const int l = idx >> 12, b = (idx >> 9) & 7, c = idx & 511;
    const float* ke = kenc + l * 4096 + b * 512;
    float a = 0.f;
    for (int i = 0; i < 512; ++i) a = fmaf(Wq[i * 512 + c], ke[i], a);
    pvec[idx] = a;
  } else if (w < 64) {
    const int idx = (w - 32) * 256 + tid;         // [l][b][j]
    const int l = idx >> 12, b = (idx >> 9) & 7, j = idx & 511;
    const float* ve = venc + l * 4096 + b * 512;
    const float* wo = Wo + (size_t)j * 512;
    float a = 0.f;
    for (int c = 0; c < 512; ++c) a = fmaf(wo[c], ve[c], a);
    veWo[idx] = a;
  } else {
    if (tid < 16) {
      const int l = tid >> 3, b = tid & 7;
      const float* ke = kenc + l * 4096 + b * 512;
      float a = 0.f;
      for (int i = 0; i < 512; ++i) a = fmaf(bq[i], ke[i], a);
      sl0[tid] = a;
    }
  }
}

// ---------------------------------------------------------------------------
// prep3: E0g/E1g = veWo @ Wout rows via LDS row-tiles (bcg moved to wing).
// ---------------------------------------------------------------------------
__global__ __launch_bounds__(256) void prep3_kernel(
    const float* Wout, const float* veWo, float* E0g, float* E1g) {
  __shared__ float sv[16 * 516];
  __shared__ float stg[8 * 516];
  const int w = blockIdx.x, tid = threadIdx.x;
  for (int e = tid; e < 8192; e += 256)
    sv[(e >> 9) * 516 + (e & 511)] = veWo[e];
  const int cbase = w * 125;
  for (int tile = 0; tile < 16; ++tile) {
    const int r0 = tile * 8;
    __syncthreads();
    for (int e = tid; e < 1024; e += 256) {
      const int rr = e >> 7, k4 = e & 127;
      int row = r0 + rr; if (row > 124) row = 124;
      *(float4*)&stg[rr * 516 + k4 * 4] =
          *(const float4*)&Wout[(size_t)(cbase + row) * 512 + k4 * 4];
    }
    __syncthreads();
    if (tid < 128) {
      const int rr = tid >> 4, sel = tid & 15;
      const int row = r0 + rr;
      if (row < 125) {
        const float4* a4 = (const float4*)&stg[rr * 516];
        const float4* x4 = (const float4*)&sv[sel * 516];
        float s0 = 0.f, s1 = 0.f, s2 = 0.f, s3 = 0.f;
#pragma unroll 8
        for (int k = 0; k < 128; ++k) {
          float4 a = a4[k], x = x4[k];
          s0 = fmaf(a.x, x.x, s0); s1 = fmaf(a.y, x.y, s1);
          s2 = fmaf(a.z, x.z, s2); s3 = fmaf(a.w, x.w, s3);
        }
        const float s = (s0 + s1) + (s2 + s3);
        (sel < 8 ? E0g : E1g)[(size_t)(sel & 7) * 32000 + cbase + row] = s;
      }
    }
  }
}

// ---------------------------------------------------------------------------
// Decoder: 256 WGs x 256 thr, 12 steps x 3 one-hop barriers (R8, unchanged).
// ---------------------------------------------------------------------------
struct DecP {
  const float* emb;
  const float* Wih; const float* Whh; const float* bih; const float* bhh;
  const float* Wout;
  const float* At; const float* W2; const float* u; const float* bvo;
  const float* pvec; const float* sl0; const float* sbb;
  const float* E0g; const float* E1g; const float* bcg;
  float* nhb; float* ncb;  // [2][32][512]
  float* vbuf;             // [32][512]
  float* part_s;           // [3][32][64]
  ull* pvp;                // [256][32][4] packed (val,idx)
  int* obh;                // [12][4][8]
  int* res0;               // [13][8]
  __hip_bfloat16* hist;    // [12][32][32000]
  int* fl;
};

__global__ __launch_bounds__(256, 1) void dec_kernel(DecP P) {
  __shared__ float SM[29600];
  __shared__ float gl[2][4][32];
  __shared__ float slS[32][3];
  __shared__ float wslS[96];
  __shared__ float svv[32][8][4];
  __shared__ int sii[32][8][4];
  __shared__ float rvS[32][4];
  __shared__ int rtS[32][4];
  __shared__ int resS[4][13][8];
  __shared__ int oblS[32];
  __shared__ int tokS[32];
  __shared__ float pscS[32][8];
  __shared__ float nhsS[32][8];

  const int w = blockIdx.x, tid = threadIdx.x;
  float* hs = SM;
  float* tileS = SM;
  float* vqS = SM + 16896;
  float* tvE = SM + 21120;
  int* tiE = (int*)(SM + 25344);
  int ph = 0;

  if (tid < 104) {
    for (int n = 0; n < 4; ++n) resS[n][tid >> 3][tid & 7] = 1;
  }

  auto do_select = [&](int tt) {
    {
      const int r = tid >> 3, ch = tid & 7;
      float m4[4] = {-FLT_MAX, -FLT_MAX, -FLT_MAX, -FLT_MAX};
      int mi[4] = {0x7fffffff, 0x7fffffff, 0x7fffffff, 0x7fffffff};
      for (int g = 0; g < 4; ++g) {
        ull pk[32];
#pragma unroll
        for (int z = 0; z < 32; ++z) {
          const int wg = ch * 32 + g * 8 + (z >> 2);
          pk[z] = cLoad64(P.pvp + wg * 128 + r * 4 + (z & 3));
        }
#pragma unroll
        for (int z = 0; z < 32; ++z)
          ins4(m4, mi, __uint_as_float((unsigned)(pk[z] >> 32)),
               (int)(unsigned)(pk[z] & 0xffffffffu));
      }
#pragma unroll
      for (int k = 0; k < 4; ++k) { svv[r][ch][k] = m4[k]; sii[r][ch][k] = mi[k]; }
    }
    __syncthreads();
    if (tid < 32) {
      float m4[4] = {-FLT_MAX, -FLT_MAX, -FLT_MAX, -FLT_MAX};
      int mi[4] = {0x7fffffff, 0x7fffffff, 0x7fffffff, 0x7fffffff};
      for (int g2 = 0; g2 < 8; ++g2)
#pragma unroll
        for (int k = 0; k < 4; ++k) ins4(m4, mi, svv[tid][g2][k], sii[tid][g2][k]);
#pragma unroll
      for (int k = 0; k < 4; ++k) { rvS[tid][k] = m4[k]; rtS[tid][k] = mi[k]; }
    }
    __syncthreads();
    if (tid < 8) {
      const int b2 = tid;
      unsigned used = 0;
      int obl_[4], tkl_[4];
#pragma unroll
      for (int sel = 0; sel < 4; ++sel) {
        float bestv = -FLT_MAX; int bestj = -1;
        for (int j = 0; j < 16; ++j) {
          if (used & (1u << j)) continue;
          float vv = rvS[(j >> 2) * 8 + b2][j & 3];
          if (vv > bestv) { bestv = vv; bestj = j; }
        }
        used |= 1u << bestj;
        const int obn = bestj >> 2;
        obl_[sel] = obn;
        tkl_[sel] = rtS[obn * 8 + b2][bestj & 3];
        oblS[sel * 8 + b2] = obn;
        tokS[sel * 8 + b2] = tkl_[sel];
        if (w == 0) P.obh[tt * 32 + sel * 8 + b2] = obn;
      }
      if (w == 0) {
        int tmp[4][13];
        for (int n2 = 0; n2 < 4; ++n2)
          for (int s2 = 0; s2 < 13; ++s2) tmp[n2][s2] = resS[obl_[n2]][s2][b2];
        for (int n2 = 0; n2 < 4; ++n2)
          for (int s2 = 0; s2 < 13; ++s2) resS[n2][s2][b2] = tmp[n2][s2];
        for (int n2 = 0; n2 < 4; ++n2) resS[n2][tt + 1][b2] = tkl_[n2];
      }
    }
    __syncthreads();
    if (tt == 11 && w == 0 && tid < 104)
      P.res0[tid] = resS[0][tid >> 3][tid & 7];
  };

  for (int t = 0; t < 12; ++t) {
    const int curOff = (t & 1) * 16384, prevOff = ((t + 1) & 1) * 16384;

    if (t == 0) {
      __syncthreads();
      if (tid < 32) { oblS[tid] = tid >> 3; tokS[tid] = 1; }
      __syncthreads();
    } else {
      do_select(t - 1);
    }
    // ===== A: LSTM gates + cell with backpointer gather =====
    {
      const int col_l = tid >> 7, gate = (tid >> 5) & 3, nb = tid & 31;
      const int col = 2 * w + col_l;
      const int row = gate * 512 + col;
      for (int e = tid; e < 2048; e += 256) {
        const int nb2 = e >> 6, kf = e & 63;
        float4 v = *((const float4*)(P.emb + (size_t)tokS[nb2] * 256) + kf);
        *((float4*)hs + nb2 * 65 + kf) = v;
      }
      __syncthreads();
      float s0 = 0.f, s1 = 0.f, s2 = 0.f, s3 = 0.f;
      {
        const float4* a4 = (const float4*)(P.Wih + (size_t)row * 256);
        const float4* x4 = (const float4*)hs + nb * 65;
#pragma unroll 8
        for (int k = 0; k < 64; ++k) {
          float4 a = a4[k], x = x4[k];
          s0 = fmaf(a.x, x.x, s0); s1 = fmaf(a.y, x.y, s1);
          s2 = fmaf(a.z, x.z, s2); s3 = fmaf(a.w, x.w, s3);
        }
      }
      float acc = P.bih[row] + P.bhh[row];
      const ull* hsrc = (const ull*)(P.nhb + prevOff);
      const float4* w4row = (const float4*)(P.Whh + (size_t)row * 512);
      for (int ck = 0; ck < 2; ++ck) {
        __syncthreads();
        for (int e = tid; e < 4096; e += 256) {
          const int nb2 = e >> 7, k2 = e & 127;
          const int srow = oblS[nb2] * 8 + (nb2 & 7);
          ull v = cLoad64(hsrc + srow * 256 + ck * 128 + k2);
          *(ull*)(hs + nb2 * 260 + 2 * k2) = v;
        }
        __syncthreads();
        const float4* h4 = (const float4*)hs + nb * 65;
        const float4* w4 = w4row + ck * 64;
#pragma unroll 8
        for (int k = 0; k < 64; ++k) {
          float4 a = w4[k], x = h4[k];
          s0 = fmaf(a.x, x.x, s0); s1 = fmaf(a.y, x.y, s1);
          s2 = fmaf(a.z, x.z, s2); s3 = fmaf(a.w, x.w, s3);
        }
      }
      acc += (s0 + s1) + (s2 + s3);
      gl[col_l][gate][nb] = acc;
      __syncthreads();
      if (tid < 64) {
        const int cc = tid >> 5, nb2 = tid & 31;
        const int col2 = 2 * w + cc;
        float gi = gl[cc][0][nb2], gf_ = gl[cc][1][nb2];
        float gg = gl[cc][2][nb2], go = gl[cc][3][nb2];
        const int srow = oblS[nb2] * 8 + (nb2 & 7);
        float cold = cLoad(P.ncb + prevOff + srow * 512 + col2);
        float c2 = sig_(gf_) * cold + sig_(gi) * tanhf(gg);
        float hv = sig_(go) * tanhf(c2);
        cStore(P.nhb + curOff + nb2 * 512 + col2, hv);
        cStore(P.ncb + curOff + nb2 * 512 + col2, c2);
      }
    }
    fbar1(P.fl, ++ph);

    // ===== B: p=0 -> score partials (At fold); p=1 -> vbuf (W2 fold) =====
    if (w < 128) {
      const int p = w >> 6, cb = w & 63;
      const int col_l = tid >> 5, nb = tid & 31;
      const int col = cb * 8 + col_l;
      const float* W = (p ? P.W2 : P.At) + (size_t)col * 512;
      float acc = (p ? P.bvo : P.u)[col];
      {
        const float4* w4row = (const float4*)W;
        float s0 = 0.f, s1 = 0.f, s2 = 0.f, s3 = 0.f;
        for (int ck = 0; ck < 2; ++ck) {
          __syncthreads();
          const ull* s8 = (const ull*)(P.nhb + curOff);
          for (int e = tid; e < 4096; e += 256) {
            const int nb2 = e >> 7, k2 = e & 127;
            ull v = cLoad64(s8 + nb2 * 256 + ck * 128 + k2);
            *(ull*)(hs + nb2 * 260 + 2 * k2) = v;
          }
          __syncthreads();
          const float4* h4 = (const float4*)hs + nb * 65;
          const float4* w4 = w4row + ck * 64;
#pragma unroll 8
          for (int k = 0; k < 64; ++k) {
            float4 a = w4[k], x = h4[k];
            s0 = fmaf(a.x, x.x, s0); s1 = fmaf(a.y, x.y, s1);
            s2 = fmaf(a.z, x.z, s2); s3 = fmaf(a.w, x.w, s3);
          }
        }
        acc += (s0 + s1) + (s2 + s3);
      }
      if (p) {
        cStore(P.vbuf + nb * 512 + col, acc);
      } else {
        const float nhv = cLoad(P.nhb + curOff + nb * 512 + col);
        pscS[nb][col_l] = nhv * acc;
        nhsS[nb][col_l] = nhv;
        __syncthreads();
        if (tid < 32) {
          const int nb2 = tid, b = nb2 & 7;
          float s2a = 0.f, l0 = 0.f, l1 = 0.f;
#pragma unroll
          for (int i2 = 0; i2 < 8; ++i2) {
            s2a += pscS[nb2][i2];
            const float nv = nhsS[nb2][i2];
            l0 = fmaf(nv, P.pvec[b * 512 + cb * 8 + i2], l0);
            l1 = fmaf(nv, P.pvec[4096 + b * 512 + cb * 8 + i2], l1);
          }
          cStore(P.part_s + (0 * 32 + nb2) * 64 + cb, l0);
          cStore(P.part_s + (1 * 32 + nb2) * 64 + cb, l1);
          cStore(P.part_s + (2 * 32 + nb2) * 64 + cb, s2a);
        }
      }
    }
    fbar1(P.fl, ++ph);

    // ===== E: softmax (from partials) + logits via LDS-tiled Wout + top-4 ==
    {
      const int cbase = w * 125;
      if (tid < 96) {
        const int nb = tid / 3, l = tid - (tid / 3) * 3, b = nb & 7;
        const ull* ps = (const ull*)(P.part_s + (l * 32 + nb) * 64);
        ull pk[32];
#pragma unroll
        for (int z = 0; z < 32; ++z) pk[z] = cLoad64(ps + z);
        float s = 0.f;
#pragma unroll
        for (int z = 0; z < 32; ++z) { float2 f = u2f2(pk[z]); s += f.x + f.y; }
        const float bias = (l < 2) ? P.sl0[l * 8 + b] : P.sbb[0];
        slS[nb][l] = (s + bias) * (1.0f / sqrtf(512.0f));
      }
      __syncthreads();
      if (tid < 32) {
        float a = slS[tid][0], b2 = slS[tid][1], c3 = slS[tid][2];
        float m = fmaxf(a, fmaxf(b2, c3));
        float e0 = expf(a - m), e1 = expf(b2 - m), e2 = expf(c3 - m);
        float inv = 1.0f / (e0 + e1 + e2);
        wslS[tid * 3 + 0] = e0 * inv;
        wslS[tid * 3 + 1] = e1 * inv;
        wslS[tid * 3 + 2] = e2 * inv;
      }
      const int rg = tid >> 3, ng = tid & 7;
      float acc[4][4];
#pragma unroll
      for (int i = 0; i < 4; ++i)
#pragma unroll
        for (int j = 0; j < 4; ++j) acc[i][j] = 0.f;
      for (int q = 0; q < 4; ++q) {
        __syncthreads();
        for (int e = tid; e < 1024; e += 256) {
          const int nb = e >> 5, kf = e & 31;
          ull u0 = cLoad64((const ull*)(P.vbuf + nb * 512 + q * 128 + kf * 4));
          ull u1 = cLoad64((const ull*)(P.vbuf + nb * 512 + q * 128 + kf * 4 + 2));
          float2 a = u2f2(u0), b2 = u2f2(u1);
          float4 v = {a.x, a.y, b2.x, b2.y};
          *(float4*)(vqS + (nb & 3) * 1056 + (nb >> 2) * 132 + kf * 4) = v;
        }
        for (int it = 0; it < 16; ++it) {
          const int idx = it * 256 + tid;
          if (idx < 4000) {
            const int r = idx >> 5, kf = idx & 31;
            float4 v = *(const float4*)(P.Wout + (size_t)(cbase + r) * 512 +
                                        q * 128 + kf * 4);
            *(float4*)(tileS + (r & 3) * 4224 + (r >> 2) * 132 + kf * 4) = v;
          }
        }
        __syncthreads();
        for (int kf = 0; kf < 32; ++kf) {
          float4 xv[4], wv[4];
#pragma unroll
          for (int j = 0; j < 4; ++j)
            xv[j] = *(const float4*)(vqS + j * 1056 + ng * 132 + kf * 4);
#pragma unroll
          for (int i = 0; i < 4; ++i)
            wv[i] = *(const float4*)(tileS + i * 4224 + rg * 132 + kf * 4);
#pragma unroll
          for (int i = 0; i < 4; ++i)
#pragma unroll
            for (int j = 0; j < 4; ++j) {
              float a = acc[i][j];
              a = fmaf(wv[i].x, xv[j].x, a); a = fmaf(wv[i].y, xv[j].y, a);
              a = fmaf(wv[i].z, xv[j].z, a); a = fmaf(wv[i].w, xv[j].w, a);
              acc[i][j] = a;
            }
        }
      }
      __syncthreads();
      float w0w[4], w1w[4], w2w[4];
#pragma unroll
      for (int j = 0; j < 4; ++j) {
        const int nb = ng * 4 + j;
        w0w[j] = wslS[nb * 3 + 0]; w1w[j] = wslS[nb * 3 + 1]; w2w[j] = wslS[nb * 3 + 2];
      }
      float v4[4][4]; int i4[4][4];
#pragma unroll
      for (int j = 0; j < 4; ++j)
#pragma unroll
        for (int k = 0; k < 4; ++k) { v4[j][k] = -FLT_MAX; i4[j][k] = 0x7fffffff; }
#pragma unroll
      for (int i = 0; i < 4; ++i) {
        const int r = rg * 4 + i;
        if (r < 125) {
          const int c = cbase + r;
          const float bcv = P.bcg[c];
#pragma unroll
          for (int j = 0; j < 4; ++j) {
            const int nb = ng * 4 + j, b = nb & 7;
            const float e0 = P.E0g[(size_t)b * 32000 + c];
            const float e1 = P.E1g[(size_t)b * 32000 + c];
            const float L = fmaf(w2w[j], acc[i][j],
                                 fmaf(w0w[j], e0, fmaf(w1w[j], e1, bcv)));
            P.hist[(size_t)t * 1024000 + (size_t)nb * 32000 + c] = __float2bfloat16(L);
            ins4(v4[j], i4[j], L, c);
          }
        }
      }
#pragma unroll
      for (int j = 0; j < 4; ++j)
#pragma unroll
        for (int k = 0; k < 4; ++k) {
          tvE[(ng * 4 + j) * 132 + rg * 4 + k] = v4[j][k];
          tiE[(ng * 4 + j) * 132 + rg * 4 + k] = i4[j][k];
        }
      __syncthreads();
      if (tid < 32) {
        float m4[4] = {-FLT_MAX, -FLT_MAX, -FLT_MAX, -FLT_MAX};
        int mi[4] = {0x7fffffff, 0x7fffffff, 0x7fffffff, 0x7fffffff};
        for (int e = 0; e < 128; ++e)
          ins4(m4, mi, tvE[tid * 132 + e], tiE[tid * 132 + e]);
#pragma unroll
        for (int k = 0; k < 4; ++k) {
          ull pk = ((ull)__float_as_uint(m4[k]) << 32) | (unsigned)mi[k];
          cStore64(P.pvp + w * 128 + tid * 4 + k, pk);
        }
      }
    }
    fbar1(P.fl, ++ph);
  }
  if (w == 0) do_select(11);
}

// ---------------------------------------------------------------------------
// Output assembly (unchanged).
// ---------------------------------------------------------------------------
__global__ __launch_bounds__(256) void out_kernel(const __hip_bfloat16* hist,
                                                  const int* obh, const int* res0,
                                                  float* out) {
  __shared__ float sh[13 * 1000];
  __shared__ int sbArr[12];
  const int w = blockIdx.x, tid = threadIdx.x;
  const int b = w >> 5, v0 = (w & 31) * 1000;
  if (tid == 0) {
    int beta = 0;
    for (int t = 11; t >= 0; --t) {
      const int sb = obh[t * 32 + beta * 8 + b];
      sbArr[t] = sb;
      beta = sb;
    }
  }
  __syncthreads();
  for (int e = tid; e < 12000; e += 256) {
    const int t = e / 1000, vv = e - t * 1000;
    sh[(t + 1) * 1000 + vv] = __bfloat162float(
        hist[(size_t)(t * 32 + sbArr[t] * 8 + b) * 32000 + v0 + vv]);
  }
  for (int e = tid; e < 1000; e += 256) sh[e] = (v0 + e == 1) ? 1.0f : 0.0f;
  __syncthreads();
  float* base = out + 104 + (size_t)(b * 32000 + v0) * 13;
  for (int o = tid; o < 13000; o += 256) {
    const int v = o / 13, t = o - v * 13;
    base[o] = sh[t * 1000 + v];
  }
  if (w == 0 && tid < 104) {
    out[(tid & 7) * 13 + (tid >> 3)] = (float)res0[tid];
  }
}

// ---------------------------------------------------------------------------
extern "C" void kernel_launch(void* const* d_in, const int* in_sizes, int n_in,
                              void* d_out, int out_size, void* d_ws, size_t ws_size,
                              hipStream_t stream) {
  const int* text  = (const int*)d_in[0];
  const float* embE = (const float*)d_in[1];
  const float* embD = (const float*)d_in[2];
  const float* Wih0 = (const float*)d_in[3];
  const float* Whh0 = (const float*)d_in[4];
  const float* bih0 = (const float*)d_in[5];
  const float* bhh0 = (const float*)d_in[6];
  const float* Wih1 = (const float*)d_in[7];
  const float* Whh1 = (const float*)d_in[8];
  const float* bih1 = (const float*)d_in[9];
  const float* bhh1 = (const float*)d_in[10];
  const float* dWih = (const float*)d_in[11];
  const float* dWhh = (const float*)d_in[12];
  const float* dbih = (const float*)d_in[13];
  const float* dbhh = (const float*)d_in[14];
  const float* Wq = (const float*)d_in[15];
  const float* bq = (const float*)d_in[16];
  const float* Wk = (const float*)d_in[17];
  const float* bk = (const float*)d_in[18];
  const float* Wv = (const float*)d_in[19];
  const float* bv = (const float*)d_in[20];
  const float* Wo = (const float*)d_in[21];
  const float* bo = (const float*)d_in[22];
  const float* Wout = (const float*)d_in[23];
  const float* bout = (const float*)d_in[24];

  char* ws = (char*)d_ws;
  size_t off = 0;
  auto alloc = [&](size_t bytes) -> char* {
    off = (off + 511) & ~(size_t)511;
    char* p = ws + off;
    off += bytes;
    return p;
  };
  float* h0hist = (float*)alloc((size_t)513 * 4096 * 4);  // 8.4 MB
  float* h1hist = (float*)alloc((size_t)513 * 4096 * 4);  // 8.4 MB
  int* decFl  = (int*)alloc((size_t)262144 * 4);          // [256][32] lines
  float* h0f  = (float*)alloc(4096 * 4);
  float* h1f  = (float*)alloc(4096 * 4);
  float* c1f  = (float*)alloc(4096 * 4);
  float* kenc = (float*)alloc(8192 * 4);
  float* venc = (float*)alloc(8192 * 4);
  float* At   = (float*)alloc((size_t)262144 * 4);
  float* W2   = (float*)alloc((size_t)262144 * 4);
  float* u    = (float*)alloc(512 * 4);
  float* pvec = (float*)alloc(8192 * 4);
  float* veWo = (float*)alloc(8192 * 4);
  float* bvo  = (float*)alloc(512 * 4);
  float* sl0  = (float*)alloc(16 * 4);
  float* sbb  = (float*)alloc(32 * 4);
  float* E0g  = (float*)alloc((size_t)256000 * 4);
  float* E1g  = (float*)alloc((size_t)256000 * 4);
  float* bcg  = (float*)alloc(32000 * 4);
  float* nhb  = (float*)alloc(2 * 16384 * 4);
  float* ncb  = (float*)alloc(2 * 16384 * 4);
  float* vbuf = (float*)alloc(16384 * 4);
  float* part_s = (float*)alloc(6144 * 4);
  ull* pvp    = (ull*)alloc((size_t)32768 * 8);
  int* obh    = (int*)alloc(384 * 4);
  int* res0   = (int*)alloc(104 * 4);
  __hip_bfloat16* hist = (__hip_bfloat16*)alloc((size_t)12288000 * 2);
  if (off > ws_size) return;  // ~49 MB required

  // sentinel-fill the dataflow buffers (0xFF bytes -> -NaN per float lane)
  hipMemsetAsync(h0hist, 0xFF, (size_t)513 * 4096 * 4, stream);
  hipMemsetAsync(h1hist, 0xFF, (size_t)513 * 4096 * 4, stream);
  hipMemsetAsync(decFl, 0, (size_t)262144 * 4, stream);

  EncP ep{text, embE, Wih0, Whh0, bih0, bhh0, Wih1, Whh1, bih1, bhh1,
          h0hist, h1hist, h0f, h1f, c1f,
          Wq, Wk, Wv, Wo, bq, bk, bv, bo, Wout, bout,
          At, W2, u, bvo, sbb, bcg};
  enc_kernel<<<512, 256, 0, stream>>>(ep);

  prep_kernel<<<128, 256, 0, stream>>>(Wk, bk, Wv, bv, h0f, h1f, c1f, kenc, venc,
                                       nhb, ncb);
  prep2b_kernel<<<65, 256, 0, stream>>>(Wq, Wo, bq, kenc, venc, pvec, veWo, sl0);
  prep3_kernel<<<256, 256, 0, stream>>>(Wout, veWo, E0g, E1g);

  DecP dp{embD, dWih, dWhh, dbih, dbhh, Wout,
          At, W2, u, bvo, pvec, sl0, sbb, E0g, E1g, bcg,
          nhb, ncb, vbuf, part_s, pvp, obh, res0, hist, decFl};
  dec_kernel<<<256, 256, 0, stream>>>(dp);

  out_kernel<<<256, 256, 0, stream>>>(hist, obh, res0, (float*)d_out);
}